// Round 2
// baseline (1399.851 us; speedup 1.0000x reference)
//
#include <hip/hip_runtime.h>

// ---------------------------------------------------------------------------
// Fused multi-head attention (B=4, N=2048, D=1024, H=16, dk=dv=64, causal)
// Strategy: bf16 MFMA throughout; Q/K path uses split-bf16 (hi/lo, 3 MFMAs)
// for ~fp32-accurate logits (sigma~1024, ties need abs err << 1).
// bf16 is handled at bit level (short), matching the guide's verified
// fragment types for __builtin_amdgcn_mfma_f32_16x16x32_bf16.
// ---------------------------------------------------------------------------

typedef short bf16;  // bf16 stored as raw bits
typedef short bf16x8 __attribute__((ext_vector_type(8)));
typedef short bf16x4 __attribute__((ext_vector_type(4)));
typedef float f32x4  __attribute__((ext_vector_type(4)));

constexpr int B_ = 4, N_ = 2048, D_ = 1024, H_ = 16, DK_ = 64;

static __device__ __forceinline__ bf16 f2bf(float f) {  // RNE float->bf16
    union { float f; unsigned u; } x; x.f = f;
    const unsigned r = x.u + 0x7FFFu + ((x.u >> 16) & 1u);
    return (bf16)(r >> 16);
}
static __device__ __forceinline__ float bf2f(bf16 s) {
    union { unsigned u; float f; } x; x.u = ((unsigned)(unsigned short)s) << 16;
    return x.f;
}

static __device__ __forceinline__ f32x4 mfma16(bf16x8 a, bf16x8 b, f32x4 c) {
    return __builtin_amdgcn_mfma_f32_16x16x32_bf16(a, b, c, 0, 0, 0);
}

// ---------------------------------------------------------------------------
// Kernel 0: prep — cast v to bf16; transpose (+split) weights so that all
// MFMA fragment loads in later kernels are contiguous 16B loads.
//   wqT/wkT: [H][dk][D] hi+lo bf16 (transposed from [H][D][dk])
//   wvT:     [H][dv][D] bf16
//   woT:     [D(out_col)][D(k)] bf16 (transposed from [D][D])
// ---------------------------------------------------------------------------
__global__ __launch_bounds__(256) void prep_kernel(
    const float* __restrict__ v,  const float* __restrict__ wq,
    const float* __restrict__ wk, const float* __restrict__ wv,
    const float* __restrict__ wo,
    bf16* __restrict__ v_bf,
    bf16* __restrict__ wqT_hi, bf16* __restrict__ wqT_lo,
    bf16* __restrict__ wkT_hi, bf16* __restrict__ wkT_lo,
    bf16* __restrict__ wvT, bf16* __restrict__ woT) {
    const int sec  = blockIdx.y;
    const int tid  = blockIdx.x * blockDim.x + threadIdx.x;
    const int nthr = gridDim.x * blockDim.x;
    if (sec == 0) {                       // v -> bf16, 4-wide
        const int n4 = (B_ * N_ * D_) / 4;
        for (int i = tid; i < n4; i += nthr) {
            const float4 f = reinterpret_cast<const float4*>(v)[i];
            bf16x4 o;
            o[0] = f2bf(f.x); o[1] = f2bf(f.y); o[2] = f2bf(f.z); o[3] = f2bf(f.w);
            reinterpret_cast<bf16x4*>(v_bf)[i] = o;
        }
    } else if (sec == 1 || sec == 2) {    // wq / wk transpose + split
        const float* w  = (sec == 1) ? wq : wk;
        bf16* whi = (sec == 1) ? wqT_hi : wkT_hi;
        bf16* wlo = (sec == 1) ? wqT_lo : wkT_lo;
        for (int i = tid; i < H_ * DK_ * D_; i += nthr) {
            const int k = i & (D_ - 1);
            const int c = (i >> 10) & (DK_ - 1);
            const int h = i >> 16;
            const float f = w[((size_t)h * D_ + k) * DK_ + c];
            const bf16 hi = f2bf(f);
            whi[i] = hi;
            wlo[i] = f2bf(f - bf2f(hi));
        }
    } else if (sec == 3) {                // wv transpose (single bf16)
        for (int i = tid; i < H_ * DK_ * D_; i += nthr) {
            const int k = i & (D_ - 1);
            const int d = (i >> 10) & (DK_ - 1);
            const int h = i >> 16;
            wvT[i] = f2bf(wv[((size_t)h * D_ + k) * DK_ + d]);
        }
    } else {                              // wo transpose (single bf16)
        for (int i = tid; i < D_ * D_; i += nthr) {
            const int k = i & (D_ - 1);
            const int c = i >> 10;
            woT[i] = f2bf(wo[(size_t)k * D_ + c]);
        }
    }
}

// ---------------------------------------------------------------------------
// Kernel 1: Q/K projection, split-bf16 (3 MFMAs per product).
// grid (8192/128, 2*H). Output qh/kh as hi+lo bf16 [B,H,N,dk].
// Q is pre-scaled by 1/sqrt(dk)=0.125 (exact pow2) so logits need no scale.
// ---------------------------------------------------------------------------
__global__ __launch_bounds__(256) void proj_qk_kernel(
    const float* __restrict__ q, const float* __restrict__ k,
    const bf16* __restrict__ wqT_hi, const bf16* __restrict__ wqT_lo,
    const bf16* __restrict__ wkT_hi, const bf16* __restrict__ wkT_lo,
    bf16* __restrict__ qh_hi, bf16* __restrict__ qh_lo,
    bf16* __restrict__ kh_hi, bf16* __restrict__ kh_lo) {
    const int mat = blockIdx.y >> 4;       // 0=q, 1=k
    const int h   = blockIdx.y & 15;
    const float* x      = mat ? k      : q;
    const bf16* wT_hi   = mat ? wkT_hi : wqT_hi;
    const bf16* wT_lo   = mat ? wkT_lo : wqT_lo;
    bf16* out_hi        = mat ? kh_hi  : qh_hi;
    bf16* out_lo        = mat ? kh_lo  : qh_lo;
    const float scale   = mat ? 1.0f : 0.125f;

    const int m0 = blockIdx.x * 128;
    const int w  = threadIdx.x >> 6;
    const int l  = threadIdx.x & 63;
    const int lr = l & 15, lg = l >> 4;

    f32x4 acc[2][4] = {};
    for (int kk = 0; kk < D_; kk += 32) {
        bf16x8 a_hi[2], a_lo[2];
#pragma unroll
        for (int mf = 0; mf < 2; ++mf) {
            const int row = m0 + w * 32 + mf * 16 + lr;
            const float4* ap =
                reinterpret_cast<const float4*>(x + (size_t)row * D_ + kk + lg * 8);
            const float4 f0 = ap[0], f1 = ap[1];
            const float ff[8] = {f0.x, f0.y, f0.z, f0.w, f1.x, f1.y, f1.z, f1.w};
#pragma unroll
            for (int j = 0; j < 8; ++j) {
                const float f  = ff[j] * scale;
                const bf16 hi = f2bf(f);
                a_hi[mf][j] = hi;
                a_lo[mf][j] = f2bf(f - bf2f(hi));
            }
        }
#pragma unroll
        for (int nf = 0; nf < 4; ++nf) {
            const size_t boff = ((size_t)h * DK_ + nf * 16 + lr) * D_ + kk + lg * 8;
            const bf16x8 b_hi = *reinterpret_cast<const bf16x8*>(wT_hi + boff);
            const bf16x8 b_lo = *reinterpret_cast<const bf16x8*>(wT_lo + boff);
#pragma unroll
            for (int mf = 0; mf < 2; ++mf) {
                acc[mf][nf] = mfma16(a_hi[mf], b_hi, acc[mf][nf]);
                acc[mf][nf] = mfma16(a_hi[mf], b_lo, acc[mf][nf]);
                acc[mf][nf] = mfma16(a_lo[mf], b_hi, acc[mf][nf]);
            }
        }
    }
#pragma unroll
    for (int mf = 0; mf < 2; ++mf)
#pragma unroll
        for (int nf = 0; nf < 4; ++nf)
#pragma unroll
            for (int i = 0; i < 4; ++i) {
                const int m = m0 + w * 32 + mf * 16 + lg * 4 + i;
                const int b = m >> 11, n = m & (N_ - 1);
                const int c = nf * 16 + lr;
                const float val = acc[mf][nf][i];
                const bf16 hi = f2bf(val);
                const size_t oidx = (((size_t)(b * H_ + h)) * N_ + n) * DK_ + c;
                out_hi[oidx] = hi;
                out_lo[oidx] = f2bf(val - bf2f(hi));
            }
}

// ---------------------------------------------------------------------------
// Kernel 2: V projection with swapped operands -> vhT [B,H,dv,N] (bf16),
// so PV B-fragments later are contiguous. grid (N/64, B*H).
// ---------------------------------------------------------------------------
__global__ __launch_bounds__(256) void proj_v_kernel(
    const bf16* __restrict__ v_bf, const bf16* __restrict__ wvT,
    bf16* __restrict__ vhT) {
    const int bh = blockIdx.y;
    const int b = bh >> 4, h = bh & 15;
    const int s0 = blockIdx.x * 64;
    const int w = threadIdx.x >> 6, l = threadIdx.x & 63;
    const int lr = l & 15, lg = l >> 4;

    f32x4 acc[4] = {};
    for (int kk = 0; kk < D_; kk += 32) {
        const bf16x8 a = *reinterpret_cast<const bf16x8*>(
            wvT + ((size_t)h * DK_ + w * 16 + lr) * D_ + kk + lg * 8);
#pragma unroll
        for (int nf = 0; nf < 4; ++nf) {
            const bf16x8 bb = *reinterpret_cast<const bf16x8*>(
                v_bf + ((size_t)b * N_ + s0 + nf * 16 + lr) * D_ + kk + lg * 8);
            acc[nf] = mfma16(a, bb, acc[nf]);
        }
    }
#pragma unroll
    for (int nf = 0; nf < 4; ++nf)
#pragma unroll
        for (int i = 0; i < 4; ++i) {
            const int d = w * 16 + lg * 4 + i;
            const int s = s0 + nf * 16 + lr;
            vhT[(((size_t)(b * H_ + h)) * DK_ + d) * N_ + s] = f2bf(acc[nf][i]);
        }
}

// ---------------------------------------------------------------------------
// Kernel 3: causal flash attention. grid (N/64, B*H), 4 waves x 16 q-rows.
// Split-bf16 QK^T (logit abs err ~0.01), online softmax in registers,
// P via per-wave XOR-swizzled LDS, PV single bf16. Output o_flat [B*N][H*dv].
// ---------------------------------------------------------------------------
__global__ __launch_bounds__(256) void attn_kernel(
    const bf16* __restrict__ qh_hi, const bf16* __restrict__ qh_lo,
    const bf16* __restrict__ kh_hi, const bf16* __restrict__ kh_lo,
    const bf16* __restrict__ vhT, bf16* __restrict__ o_flat) {
    __shared__ __align__(16) unsigned char plds[4 * 2048];
    const int bh = blockIdx.y;
    const int b = bh >> 4, h = bh & 15;
    const int qt = blockIdx.x;
    const int w = threadIdx.x >> 6, l = threadIdx.x & 63;
    const int lr = l & 15, lg = l >> 4;
    const int q0 = qt * 64 + w * 16;
    unsigned char* myp = plds + w * 2048;
    const size_t hb = (size_t)(b * H_ + h);

    bf16x8 qf_hi[2], qf_lo[2];
#pragma unroll
    for (int ks = 0; ks < 2; ++ks) {
        const size_t off = (hb * N_ + q0 + lr) * DK_ + ks * 32 + lg * 8;
        qf_hi[ks] = *reinterpret_cast<const bf16x8*>(qh_hi + off);
        qf_lo[ks] = *reinterpret_cast<const bf16x8*>(qh_lo + off);
    }

    f32x4 m_run, l_run, o_acc[4];
#pragma unroll
    for (int i = 0; i < 4; ++i) { m_run[i] = -3e38f; l_run[i] = 0.f; }
#pragma unroll
    for (int dt = 0; dt < 4; ++dt) o_acc[dt] = f32x4{0.f, 0.f, 0.f, 0.f};

    const int nt = qt + 1;
    for (int t = 0; t < nt; ++t) {
        const int s0 = t * 64;
        f32x4 sacc[4];
#pragma unroll
        for (int f = 0; f < 4; ++f) {
            sacc[f] = f32x4{0.f, 0.f, 0.f, 0.f};
#pragma unroll
            for (int ks = 0; ks < 2; ++ks) {
                const size_t off = (hb * N_ + s0 + f * 16 + lr) * DK_ + ks * 32 + lg * 8;
                const bf16x8 k_hi = *reinterpret_cast<const bf16x8*>(kh_hi + off);
                const bf16x8 k_lo = *reinterpret_cast<const bf16x8*>(kh_lo + off);
                sacc[f] = mfma16(qf_hi[ks], k_hi, sacc[f]);
                sacc[f] = mfma16(qf_hi[ks], k_lo, sacc[f]);
                sacc[f] = mfma16(qf_lo[ks], k_hi, sacc[f]);
            }
        }
        if (t == nt - 1) {  // diagonal tile: mask s > q
#pragma unroll
            for (int f = 0; f < 4; ++f) {
                const int s = s0 + f * 16 + lr;
#pragma unroll
                for (int i = 0; i < 4; ++i) {
                    const int qq = q0 + lg * 4 + i;
                    if (s > qq) sacc[f][i] = -1e9f;
                }
            }
        }
        // row max over 64 s (4 frags x 16-lane group)
        f32x4 tmax;
#pragma unroll
        for (int i = 0; i < 4; ++i)
            tmax[i] = fmaxf(fmaxf(sacc[0][i], sacc[1][i]), fmaxf(sacc[2][i], sacc[3][i]));
#pragma unroll
        for (int off = 1; off < 16; off <<= 1)
#pragma unroll
            for (int i = 0; i < 4; ++i)
                tmax[i] = fmaxf(tmax[i], __shfl_xor(tmax[i], off));
        f32x4 m_new, escale;
#pragma unroll
        for (int i = 0; i < 4; ++i) {
            m_new[i]  = fmaxf(m_run[i], tmax[i]);
            escale[i] = __expf(m_run[i] - m_new[i]);
        }
        float p[4][4];
        f32x4 rsum;
#pragma unroll
        for (int i = 0; i < 4; ++i) rsum[i] = 0.f;
#pragma unroll
        for (int f = 0; f < 4; ++f)
#pragma unroll
            for (int i = 0; i < 4; ++i) {
                p[f][i] = __expf(sacc[f][i] - m_new[i]);
                rsum[i] += p[f][i];
            }
#pragma unroll
        for (int off = 1; off < 16; off <<= 1)
#pragma unroll
            for (int i = 0; i < 4; ++i) rsum[i] += __shfl_xor(rsum[i], off);
#pragma unroll
        for (int i = 0; i < 4; ++i) {
            l_run[i] = l_run[i] * escale[i] + rsum[i];
            m_run[i] = m_new[i];
        }
#pragma unroll
        for (int dt = 0; dt < 4; ++dt)
#pragma unroll
            for (int i = 0; i < 4; ++i) o_acc[dt][i] *= escale[i];
        // P -> LDS (C-layout write, swizzled), read back as A-layout
#pragma unroll
        for (int f = 0; f < 4; ++f)
#pragma unroll
            for (int i = 0; i < 4; ++i) {
                const int row = lg * 4 + i, col = f * 16 + lr;
                const int byte = (row * 128 + col * 2) ^ ((row & 7) << 4);
                *reinterpret_cast<bf16*>(myp + byte) = f2bf(p[f][i]);
            }
        bf16x8 pa[2];
#pragma unroll
        for (int ks = 0; ks < 2; ++ks) {
            const int byte = (lr * 128 + ks * 64 + lg * 16) ^ ((lr & 7) << 4);
            pa[ks] = *reinterpret_cast<const bf16x8*>(myp + byte);
        }
#pragma unroll
        for (int dt = 0; dt < 4; ++dt)
#pragma unroll
            for (int ks = 0; ks < 2; ++ks) {
                const bf16x8 vb = *reinterpret_cast<const bf16x8*>(
                    vhT + (hb * DK_ + dt * 16 + lr) * N_ + s0 + ks * 32 + lg * 8);
                o_acc[dt] = mfma16(pa[ks], vb, o_acc[dt]);
            }
    }
#pragma unroll
    for (int dt = 0; dt < 4; ++dt)
#pragma unroll
        for (int i = 0; i < 4; ++i) {
            const int qq = q0 + lg * 4 + i;
            const float val = o_acc[dt][i] / l_run[i];
            o_flat[((size_t)b * N_ + qq) * (H_ * DK_) + h * DK_ + dt * 16 + lr] = f2bf(val);
        }
}

// ---------------------------------------------------------------------------
// Kernel 4: output projection. o_flat [8192][1024] bf16 x woT -> out f32.
// grid (8192/128, 1024/64).
// ---------------------------------------------------------------------------
__global__ __launch_bounds__(256) void outproj_kernel(
    const bf16* __restrict__ o_flat, const bf16* __restrict__ woT,
    float* __restrict__ out) {
    const int m0   = blockIdx.x * 128;
    const int col0 = blockIdx.y * 64;
    const int w = threadIdx.x >> 6, l = threadIdx.x & 63;
    const int lr = l & 15, lg = l >> 4;

    f32x4 acc[2][4] = {};
    for (int kk = 0; kk < D_; kk += 32) {
        bf16x8 a[2];
#pragma unroll
        for (int mf = 0; mf < 2; ++mf)
            a[mf] = *reinterpret_cast<const bf16x8*>(
                o_flat + ((size_t)m0 + w * 32 + mf * 16 + lr) * D_ + kk + lg * 8);
#pragma unroll
        for (int nf = 0; nf < 4; ++nf) {
            const bf16x8 bb = *reinterpret_cast<const bf16x8*>(
                woT + ((size_t)col0 + nf * 16 + lr) * D_ + kk + lg * 8);
#pragma unroll
            for (int mf = 0; mf < 2; ++mf)
                acc[mf][nf] = mfma16(a[mf], bb, acc[mf][nf]);
        }
    }
#pragma unroll
    for (int mf = 0; mf < 2; ++mf)
#pragma unroll
        for (int nf = 0; nf < 4; ++nf)
#pragma unroll
            for (int i = 0; i < 4; ++i) {
                const int m = m0 + w * 32 + mf * 16 + lg * 4 + i;
                out[(size_t)m * D_ + col0 + nf * 16 + lr] = acc[mf][nf][i];
            }
}

// ---------------------------------------------------------------------------
extern "C" void kernel_launch(void* const* d_in, const int* in_sizes, int n_in,
                              void* d_out, int out_size, void* d_ws, size_t ws_size,
                              hipStream_t stream) {
    const float* q  = (const float*)d_in[0];
    const float* k  = (const float*)d_in[1];
    const float* v  = (const float*)d_in[2];
    const float* wq = (const float*)d_in[3];
    const float* wk = (const float*)d_in[4];
    const float* wv = (const float*)d_in[5];
    const float* wo = (const float*)d_in[6];
    float* out = (float*)d_out;

    char* p = (char*)d_ws;
    auto alloc = [&](size_t elems) {
        bf16* r = (bf16*)p;
        p += ((elems * 2 + 255) / 256) * 256;
        return r;
    };
    bf16* v_bf   = alloc((size_t)B_ * N_ * D_);
    bf16* wqT_hi = alloc((size_t)H_ * DK_ * D_);
    bf16* wqT_lo = alloc((size_t)H_ * DK_ * D_);
    bf16* wkT_hi = alloc((size_t)H_ * DK_ * D_);
    bf16* wkT_lo = alloc((size_t)H_ * DK_ * D_);
    bf16* wvT    = alloc((size_t)H_ * DK_ * D_);
    bf16* woT    = alloc((size_t)D_ * D_);
    bf16* qh_hi  = alloc((size_t)B_ * H_ * N_ * DK_);
    bf16* qh_lo  = alloc((size_t)B_ * H_ * N_ * DK_);
    bf16* kh_hi  = alloc((size_t)B_ * H_ * N_ * DK_);
    bf16* kh_lo  = alloc((size_t)B_ * H_ * N_ * DK_);
    bf16* vhT    = alloc((size_t)B_ * H_ * DK_ * N_);
    bf16* o_flat = alloc((size_t)B_ * N_ * H_ * DK_);

    if ((size_t)(p - (char*)d_ws) > ws_size) return;  // ws too small: bail

    prep_kernel<<<dim3(1024, 5), 256, 0, stream>>>(v, wq, wk, wv, wo, v_bf,
                                                   wqT_hi, wqT_lo, wkT_hi, wkT_lo, wvT, woT);
    proj_qk_kernel<<<dim3(64, 32), 256, 0, stream>>>(q, k, wqT_hi, wqT_lo, wkT_hi, wkT_lo,
                                                     qh_hi, qh_lo, kh_hi, kh_lo);
    proj_v_kernel<<<dim3(32, 64), 256, 0, stream>>>(v_bf, wvT, vhT);
    attn_kernel<<<dim3(32, 64), 256, 0, stream>>>(qh_hi, qh_lo, kh_hi, kh_lo, vhT, o_flat);
    outproj_kernel<<<dim3(64, 16), 256, 0, stream>>>(o_flat, woT, out);
}

// Round 3
// 1085.771 us; speedup vs baseline: 1.2893x; 1.2893x over previous
//
#include <hip/hip_runtime.h>

// ---------------------------------------------------------------------------
// Fused multi-head attention (B=4, N=2048, D=1024, H=16, dk=dv=64, causal)
// bf16 MFMA throughout; Q/K path uses split-bf16 (hi/lo, 3 MFMAs) for
// ~fp32-accurate logits (sigma~1024). R3: attn load-balanced via q-tile
// pairing (p, 31-p) -> 1024 uniform blocks, all co-resident (4 blocks/CU,
// launch_bounds(256,4)); XCD-clustered block order; V loads hoisted ahead
// of softmax.
// ---------------------------------------------------------------------------

typedef short bf16;  // bf16 stored as raw bits
typedef short bf16x8 __attribute__((ext_vector_type(8)));
typedef short bf16x4 __attribute__((ext_vector_type(4)));
typedef float f32x4  __attribute__((ext_vector_type(4)));

constexpr int B_ = 4, N_ = 2048, D_ = 1024, H_ = 16, DK_ = 64;

static __device__ __forceinline__ bf16 f2bf(float f) {  // RNE float->bf16
    union { float f; unsigned u; } x; x.f = f;
    const unsigned r = x.u + 0x7FFFu + ((x.u >> 16) & 1u);
    return (bf16)(r >> 16);
}
static __device__ __forceinline__ float bf2f(bf16 s) {
    union { unsigned u; float f; } x; x.u = ((unsigned)(unsigned short)s) << 16;
    return x.f;
}

static __device__ __forceinline__ f32x4 mfma16(bf16x8 a, bf16x8 b, f32x4 c) {
    return __builtin_amdgcn_mfma_f32_16x16x32_bf16(a, b, c, 0, 0, 0);
}

// ---------------------------------------------------------------------------
// Kernel 0: prep — cast v to bf16; transpose (+split) weights.
// ---------------------------------------------------------------------------
__global__ __launch_bounds__(256) void prep_kernel(
    const float* __restrict__ v,  const float* __restrict__ wq,
    const float* __restrict__ wk, const float* __restrict__ wv,
    const float* __restrict__ wo,
    bf16* __restrict__ v_bf,
    bf16* __restrict__ wqT_hi, bf16* __restrict__ wqT_lo,
    bf16* __restrict__ wkT_hi, bf16* __restrict__ wkT_lo,
    bf16* __restrict__ wvT, bf16* __restrict__ woT) {
    const int sec  = blockIdx.y;
    const int tid  = blockIdx.x * blockDim.x + threadIdx.x;
    const int nthr = gridDim.x * blockDim.x;
    if (sec == 0) {                       // v -> bf16, 4-wide
        const int n4 = (B_ * N_ * D_) / 4;
        for (int i = tid; i < n4; i += nthr) {
            const float4 f = reinterpret_cast<const float4*>(v)[i];
            bf16x4 o;
            o[0] = f2bf(f.x); o[1] = f2bf(f.y); o[2] = f2bf(f.z); o[3] = f2bf(f.w);
            reinterpret_cast<bf16x4*>(v_bf)[i] = o;
        }
    } else if (sec == 1 || sec == 2) {    // wq / wk transpose + split
        const float* w  = (sec == 1) ? wq : wk;
        bf16* whi = (sec == 1) ? wqT_hi : wkT_hi;
        bf16* wlo = (sec == 1) ? wqT_lo : wkT_lo;
        for (int i = tid; i < H_ * DK_ * D_; i += nthr) {
            const int k = i & (D_ - 1);
            const int c = (i >> 10) & (DK_ - 1);
            const int h = i >> 16;
            const float f = w[((size_t)h * D_ + k) * DK_ + c];
            const bf16 hi = f2bf(f);
            whi[i] = hi;
            wlo[i] = f2bf(f - bf2f(hi));
        }
    } else if (sec == 3) {                // wv transpose (single bf16)
        for (int i = tid; i < H_ * DK_ * D_; i += nthr) {
            const int k = i & (D_ - 1);
            const int d = (i >> 10) & (DK_ - 1);
            const int h = i >> 16;
            wvT[i] = f2bf(wv[((size_t)h * D_ + k) * DK_ + d]);
        }
    } else {                              // wo transpose (single bf16)
        for (int i = tid; i < D_ * D_; i += nthr) {
            const int k = i & (D_ - 1);
            const int c = i >> 10;
            woT[i] = f2bf(wo[(size_t)k * D_ + c]);
        }
    }
}

// ---------------------------------------------------------------------------
// Kernel 1: Q/K projection, split-bf16 (3 MFMAs per product).
// grid (8192/128, 2*H). Output qh/kh as hi+lo bf16 [B,H,N,dk].
// Q pre-scaled by 1/sqrt(dk)=0.125.
// ---------------------------------------------------------------------------
__global__ __launch_bounds__(256) void proj_qk_kernel(
    const float* __restrict__ q, const float* __restrict__ k,
    const bf16* __restrict__ wqT_hi, const bf16* __restrict__ wqT_lo,
    const bf16* __restrict__ wkT_hi, const bf16* __restrict__ wkT_lo,
    bf16* __restrict__ qh_hi, bf16* __restrict__ qh_lo,
    bf16* __restrict__ kh_hi, bf16* __restrict__ kh_lo) {
    const int mat = blockIdx.y >> 4;       // 0=q, 1=k
    const int h   = blockIdx.y & 15;
    const float* x      = mat ? k      : q;
    const bf16* wT_hi   = mat ? wkT_hi : wqT_hi;
    const bf16* wT_lo   = mat ? wkT_lo : wqT_lo;
    bf16* out_hi        = mat ? kh_hi  : qh_hi;
    bf16* out_lo        = mat ? kh_lo  : qh_lo;
    const float scale   = mat ? 1.0f : 0.125f;

    const int m0 = blockIdx.x * 128;
    const int w  = threadIdx.x >> 6;
    const int l  = threadIdx.x & 63;
    const int lr = l & 15, lg = l >> 4;

    f32x4 acc[2][4] = {};
    for (int kk = 0; kk < D_; kk += 32) {
        bf16x8 a_hi[2], a_lo[2];
#pragma unroll
        for (int mf = 0; mf < 2; ++mf) {
            const int row = m0 + w * 32 + mf * 16 + lr;
            const float4* ap =
                reinterpret_cast<const float4*>(x + (size_t)row * D_ + kk + lg * 8);
            const float4 f0 = ap[0], f1 = ap[1];
            const float ff[8] = {f0.x, f0.y, f0.z, f0.w, f1.x, f1.y, f1.z, f1.w};
#pragma unroll
            for (int j = 0; j < 8; ++j) {
                const float f  = ff[j] * scale;
                const bf16 hi = f2bf(f);
                a_hi[mf][j] = hi;
                a_lo[mf][j] = f2bf(f - bf2f(hi));
            }
        }
#pragma unroll
        for (int nf = 0; nf < 4; ++nf) {
            const size_t boff = ((size_t)h * DK_ + nf * 16 + lr) * D_ + kk + lg * 8;
            const bf16x8 b_hi = *reinterpret_cast<const bf16x8*>(wT_hi + boff);
            const bf16x8 b_lo = *reinterpret_cast<const bf16x8*>(wT_lo + boff);
#pragma unroll
            for (int mf = 0; mf < 2; ++mf) {
                acc[mf][nf] = mfma16(a_hi[mf], b_hi, acc[mf][nf]);
                acc[mf][nf] = mfma16(a_hi[mf], b_lo, acc[mf][nf]);
                acc[mf][nf] = mfma16(a_lo[mf], b_hi, acc[mf][nf]);
            }
        }
    }
#pragma unroll
    for (int mf = 0; mf < 2; ++mf)
#pragma unroll
        for (int nf = 0; nf < 4; ++nf)
#pragma unroll
            for (int i = 0; i < 4; ++i) {
                const int m = m0 + w * 32 + mf * 16 + lg * 4 + i;
                const int b = m >> 11, n = m & (N_ - 1);
                const int c = nf * 16 + lr;
                const float val = acc[mf][nf][i];
                const bf16 hi = f2bf(val);
                const size_t oidx = (((size_t)(b * H_ + h)) * N_ + n) * DK_ + c;
                out_hi[oidx] = hi;
                out_lo[oidx] = f2bf(val - bf2f(hi));
            }
}

// ---------------------------------------------------------------------------
// Kernel 2: V projection with swapped operands -> vhT [B,H,dv,N] (bf16).
// grid (N/64, B*H).
// ---------------------------------------------------------------------------
__global__ __launch_bounds__(256) void proj_v_kernel(
    const bf16* __restrict__ v_bf, const bf16* __restrict__ wvT,
    bf16* __restrict__ vhT) {
    const int bh = blockIdx.y;
    const int b = bh >> 4, h = bh & 15;
    const int s0 = blockIdx.x * 64;
    const int w = threadIdx.x >> 6, l = threadIdx.x & 63;
    const int lr = l & 15, lg = l >> 4;

    f32x4 acc[4] = {};
    for (int kk = 0; kk < D_; kk += 32) {
        const bf16x8 a = *reinterpret_cast<const bf16x8*>(
            wvT + ((size_t)h * DK_ + w * 16 + lr) * D_ + kk + lg * 8);
#pragma unroll
        for (int nf = 0; nf < 4; ++nf) {
            const bf16x8 bb = *reinterpret_cast<const bf16x8*>(
                v_bf + ((size_t)b * N_ + s0 + nf * 16 + lr) * D_ + kk + lg * 8);
            acc[nf] = mfma16(a, bb, acc[nf]);
        }
    }
#pragma unroll
    for (int nf = 0; nf < 4; ++nf)
#pragma unroll
        for (int i = 0; i < 4; ++i) {
            const int d = w * 16 + lg * 4 + i;
            const int s = s0 + nf * 16 + lr;
            vhT[(((size_t)(b * H_ + h)) * DK_ + d) * N_ + s] = f2bf(acc[nf][i]);
        }
}

// ---------------------------------------------------------------------------
// Kernel 3: causal flash attention, load-balanced.
// grid: 1024 blocks 1D. Block handles q-tile pair (p, 31-p) for one (b,h):
// every block = 33 KV tiles. XCD-clustered order (same bh -> same XCD L2).
// 4 waves x 16 q-rows; split-bf16 QK^T; online softmax in registers;
// V loads hoisted before softmax; P via per-wave XOR-swizzled LDS.
// ---------------------------------------------------------------------------
__global__ __launch_bounds__(256, 4) void attn_kernel(
    const bf16* __restrict__ qh_hi, const bf16* __restrict__ qh_lo,
    const bf16* __restrict__ kh_hi, const bf16* __restrict__ kh_lo,
    const bf16* __restrict__ vhT, bf16* __restrict__ o_flat) {
    __shared__ __align__(16) unsigned char plds[4 * 2048];
    // XCD-aware bijective remap: 1024 blocks, 8 XCDs, 128 blocks/XCD chunk.
    const int bid  = blockIdx.x;
    const int wgid = (bid & 7) * 128 + (bid >> 3);
    const int bh   = wgid >> 4;   // 0..63  (b*16+h)
    const int pr   = wgid & 15;   // pair index 0..15
    const int b = bh >> 4, h = bh & 15;
    const int w = threadIdx.x >> 6, l = threadIdx.x & 63;
    const int lr = l & 15, lg = l >> 4;
    unsigned char* myp = plds + w * 2048;
    const size_t hb = (size_t)(b * H_ + h);

#pragma unroll
    for (int phase = 0; phase < 2; ++phase) {
        const int qt = phase ? (31 - pr) : pr;
        const int q0 = qt * 64 + w * 16;

        bf16x8 qf_hi[2], qf_lo[2];
#pragma unroll
        for (int ks = 0; ks < 2; ++ks) {
            const size_t off = (hb * N_ + q0 + lr) * DK_ + ks * 32 + lg * 8;
            qf_hi[ks] = *reinterpret_cast<const bf16x8*>(qh_hi + off);
            qf_lo[ks] = *reinterpret_cast<const bf16x8*>(qh_lo + off);
        }

        f32x4 m_run, l_run, o_acc[4];
#pragma unroll
        for (int i = 0; i < 4; ++i) { m_run[i] = -3e38f; l_run[i] = 0.f; }
#pragma unroll
        for (int dt = 0; dt < 4; ++dt) o_acc[dt] = f32x4{0.f, 0.f, 0.f, 0.f};

        const int nt = qt + 1;
        for (int t = 0; t < nt; ++t) {
            const int s0 = t * 64;
            f32x4 sacc[4];
#pragma unroll
            for (int f = 0; f < 4; ++f) {
                sacc[f] = f32x4{0.f, 0.f, 0.f, 0.f};
#pragma unroll
                for (int ks = 0; ks < 2; ++ks) {
                    const size_t off = (hb * N_ + s0 + f * 16 + lr) * DK_ + ks * 32 + lg * 8;
                    const bf16x8 k_hi = *reinterpret_cast<const bf16x8*>(kh_hi + off);
                    const bf16x8 k_lo = *reinterpret_cast<const bf16x8*>(kh_lo + off);
                    sacc[f] = mfma16(qf_hi[ks], k_hi, sacc[f]);
                    sacc[f] = mfma16(qf_hi[ks], k_lo, sacc[f]);
                    sacc[f] = mfma16(qf_lo[ks], k_hi, sacc[f]);
                }
            }
            // V loads hoisted: independent of softmax, overlap the shfl chain
            bf16x8 vb[4][2];
#pragma unroll
            for (int dt = 0; dt < 4; ++dt)
#pragma unroll
                for (int ks = 0; ks < 2; ++ks)
                    vb[dt][ks] = *reinterpret_cast<const bf16x8*>(
                        vhT + (hb * DK_ + dt * 16 + lr) * N_ + s0 + ks * 32 + lg * 8);

            if (t == nt - 1) {  // diagonal tile: mask s > q
#pragma unroll
                for (int f = 0; f < 4; ++f) {
                    const int s = s0 + f * 16 + lr;
#pragma unroll
                    for (int i = 0; i < 4; ++i) {
                        const int qq = q0 + lg * 4 + i;
                        if (s > qq) sacc[f][i] = -1e9f;
                    }
                }
            }
            // row max over 64 s (4 frags x 16-lane group)
            f32x4 tmax;
#pragma unroll
            for (int i = 0; i < 4; ++i)
                tmax[i] = fmaxf(fmaxf(sacc[0][i], sacc[1][i]), fmaxf(sacc[2][i], sacc[3][i]));
#pragma unroll
            for (int off = 1; off < 16; off <<= 1)
#pragma unroll
                for (int i = 0; i < 4; ++i)
                    tmax[i] = fmaxf(tmax[i], __shfl_xor(tmax[i], off));
            f32x4 m_new, escale;
#pragma unroll
            for (int i = 0; i < 4; ++i) {
                m_new[i]  = fmaxf(m_run[i], tmax[i]);
                escale[i] = __expf(m_run[i] - m_new[i]);
            }
            float p[4][4];
            f32x4 rsum;
#pragma unroll
            for (int i = 0; i < 4; ++i) rsum[i] = 0.f;
#pragma unroll
            for (int f = 0; f < 4; ++f)
#pragma unroll
                for (int i = 0; i < 4; ++i) {
                    p[f][i] = __expf(sacc[f][i] - m_new[i]);
                    rsum[i] += p[f][i];
                }
#pragma unroll
            for (int off = 1; off < 16; off <<= 1)
#pragma unroll
                for (int i = 0; i < 4; ++i) rsum[i] += __shfl_xor(rsum[i], off);
#pragma unroll
            for (int i = 0; i < 4; ++i) {
                l_run[i] = l_run[i] * escale[i] + rsum[i];
                m_run[i] = m_new[i];
            }
#pragma unroll
            for (int dt = 0; dt < 4; ++dt)
#pragma unroll
                for (int i = 0; i < 4; ++i) o_acc[dt][i] *= escale[i];
            // P -> LDS (C-layout write, swizzled), read back as A-layout
#pragma unroll
            for (int f = 0; f < 4; ++f)
#pragma unroll
                for (int i = 0; i < 4; ++i) {
                    const int row = lg * 4 + i, col = f * 16 + lr;
                    const int byte = (row * 128 + col * 2) ^ ((row & 7) << 4);
                    *reinterpret_cast<bf16*>(myp + byte) = f2bf(p[f][i]);
                }
            bf16x8 pa[2];
#pragma unroll
            for (int ks = 0; ks < 2; ++ks) {
                const int byte = (lr * 128 + ks * 64 + lg * 16) ^ ((lr & 7) << 4);
                pa[ks] = *reinterpret_cast<const bf16x8*>(myp + byte);
            }
#pragma unroll
            for (int dt = 0; dt < 4; ++dt)
#pragma unroll
                for (int ks = 0; ks < 2; ++ks)
                    o_acc[dt] = mfma16(pa[ks], vb[dt][ks], o_acc[dt]);
        }
#pragma unroll
        for (int dt = 0; dt < 4; ++dt)
#pragma unroll
            for (int i = 0; i < 4; ++i) {
                const int qq = q0 + lg * 4 + i;
                const float val = o_acc[dt][i] / l_run[i];
                o_flat[((size_t)b * N_ + qq) * (H_ * DK_) + h * DK_ + dt * 16 + lr] =
                    f2bf(val);
            }
    }
}

// ---------------------------------------------------------------------------
// Kernel 4: output projection. o_flat [8192][1024] bf16 x woT -> out f32.
// grid (8192/128, 1024/64).
// ---------------------------------------------------------------------------
__global__ __launch_bounds__(256) void outproj_kernel(
    const bf16* __restrict__ o_flat, const bf16* __restrict__ woT,
    float* __restrict__ out) {
    const int m0   = blockIdx.x * 128;
    const int col0 = blockIdx.y * 64;
    const int w = threadIdx.x >> 6, l = threadIdx.x & 63;
    const int lr = l & 15, lg = l >> 4;

    f32x4 acc[2][4] = {};
    for (int kk = 0; kk < D_; kk += 32) {
        bf16x8 a[2];
#pragma unroll
        for (int mf = 0; mf < 2; ++mf)
            a[mf] = *reinterpret_cast<const bf16x8*>(
                o_flat + ((size_t)m0 + w * 32 + mf * 16 + lr) * D_ + kk + lg * 8);
#pragma unroll
        for (int nf = 0; nf < 4; ++nf) {
            const bf16x8 bb = *reinterpret_cast<const bf16x8*>(
                woT + ((size_t)col0 + nf * 16 + lr) * D_ + kk + lg * 8);
#pragma unroll
            for (int mf = 0; mf < 2; ++mf)
                acc[mf][nf] = mfma16(a[mf], bb, acc[mf][nf]);
        }
    }
#pragma unroll
    for (int mf = 0; mf < 2; ++mf)
#pragma unroll
        for (int nf = 0; nf < 4; ++nf)
#pragma unroll
            for (int i = 0; i < 4; ++i) {
                const int m = m0 + w * 32 + mf * 16 + lg * 4 + i;
                out[(size_t)m * D_ + col0 + nf * 16 + lr] = acc[mf][nf][i];
            }
}

// ---------------------------------------------------------------------------
extern "C" void kernel_launch(void* const* d_in, const int* in_sizes, int n_in,
                              void* d_out, int out_size, void* d_ws, size_t ws_size,
                              hipStream_t stream) {
    const float* q  = (const float*)d_in[0];
    const float* k  = (const float*)d_in[1];
    const float* v  = (const float*)d_in[2];
    const float* wq = (const float*)d_in[3];
    const float* wk = (const float*)d_in[4];
    const float* wv = (const float*)d_in[5];
    const float* wo = (const float*)d_in[6];
    float* out = (float*)d_out;

    char* p = (char*)d_ws;
    auto alloc = [&](size_t elems) {
        bf16* r = (bf16*)p;
        p += ((elems * 2 + 255) / 256) * 256;
        return r;
    };
    bf16* v_bf   = alloc((size_t)B_ * N_ * D_);
    bf16* wqT_hi = alloc((size_t)H_ * DK_ * D_);
    bf16* wqT_lo = alloc((size_t)H_ * DK_ * D_);
    bf16* wkT_hi = alloc((size_t)H_ * DK_ * D_);
    bf16* wkT_lo = alloc((size_t)H_ * DK_ * D_);
    bf16* wvT    = alloc((size_t)H_ * DK_ * D_);
    bf16* woT    = alloc((size_t)D_ * D_);
    bf16* qh_hi  = alloc((size_t)B_ * H_ * N_ * DK_);
    bf16* qh_lo  = alloc((size_t)B_ * H_ * N_ * DK_);
    bf16* kh_hi  = alloc((size_t)B_ * H_ * N_ * DK_);
    bf16* kh_lo  = alloc((size_t)B_ * H_ * N_ * DK_);
    bf16* vhT    = alloc((size_t)B_ * H_ * DK_ * N_);
    bf16* o_flat = alloc((size_t)B_ * N_ * H_ * DK_);

    if ((size_t)(p - (char*)d_ws) > ws_size) return;  // ws too small: bail

    prep_kernel<<<dim3(1024, 5), 256, 0, stream>>>(v, wq, wk, wv, wo, v_bf,
                                                   wqT_hi, wqT_lo, wkT_hi, wkT_lo, wvT, woT);
    proj_qk_kernel<<<dim3(64, 32), 256, 0, stream>>>(q, k, wqT_hi, wqT_lo, wkT_hi, wkT_lo,
                                                     qh_hi, qh_lo, kh_hi, kh_lo);
    proj_v_kernel<<<dim3(32, 64), 256, 0, stream>>>(v_bf, wvT, vhT);
    attn_kernel<<<1024, 256, 0, stream>>>(qh_hi, qh_lo, kh_hi, kh_lo, vhT, o_flat);
    outproj_kernel<<<dim3(64, 16), 256, 0, stream>>>(o_flat, woT, out);
}

// Round 5
// 996.730 us; speedup vs baseline: 1.4044x; 1.0893x over previous
//
#include <hip/hip_runtime.h>

// ---------------------------------------------------------------------------
// Fused multi-head attention (B=4, N=2048, D=1024, H=16, dk=dv=64, causal)
// bf16 MFMA throughout; Q/K path uses split-bf16 (hi/lo, 3 MFMAs) for
// ~fp32-accurate logits. R4 (resubmit): proj_qk and outproj rewritten with
// LDS-staged A-tiles (XOR-swizzled, coalesced staging loads) to kill
// per-lane row-strided global fragment loads. attn/prep/proj_v unchanged.
// ---------------------------------------------------------------------------

typedef short bf16;  // bf16 stored as raw bits
typedef short bf16x8 __attribute__((ext_vector_type(8)));
typedef short bf16x4 __attribute__((ext_vector_type(4)));
typedef float f32x4  __attribute__((ext_vector_type(4)));

constexpr int B_ = 4, N_ = 2048, D_ = 1024, H_ = 16, DK_ = 64;

static __device__ __forceinline__ bf16 f2bf(float f) {  // RNE float->bf16
    union { float f; unsigned u; } x; x.f = f;
    const unsigned r = x.u + 0x7FFFu + ((x.u >> 16) & 1u);
    return (bf16)(r >> 16);
}
static __device__ __forceinline__ float bf2f(bf16 s) {
    union { unsigned u; float f; } x; x.u = ((unsigned)(unsigned short)s) << 16;
    return x.f;
}

static __device__ __forceinline__ f32x4 mfma16(bf16x8 a, bf16x8 b, f32x4 c) {
    return __builtin_amdgcn_mfma_f32_16x16x32_bf16(a, b, c, 0, 0, 0);
}

// ---------------------------------------------------------------------------
// Kernel 0: prep — cast v to bf16; transpose (+split) weights. (unchanged)
// ---------------------------------------------------------------------------
__global__ __launch_bounds__(256) void prep_kernel(
    const float* __restrict__ v,  const float* __restrict__ wq,
    const float* __restrict__ wk, const float* __restrict__ wv,
    const float* __restrict__ wo,
    bf16* __restrict__ v_bf,
    bf16* __restrict__ wqT_hi, bf16* __restrict__ wqT_lo,
    bf16* __restrict__ wkT_hi, bf16* __restrict__ wkT_lo,
    bf16* __restrict__ wvT, bf16* __restrict__ woT) {
    const int sec  = blockIdx.y;
    const int tid  = blockIdx.x * blockDim.x + threadIdx.x;
    const int nthr = gridDim.x * blockDim.x;
    if (sec == 0) {                       // v -> bf16, 4-wide
        const int n4 = (B_ * N_ * D_) / 4;
        for (int i = tid; i < n4; i += nthr) {
            const float4 f = reinterpret_cast<const float4*>(v)[i];
            bf16x4 o;
            o[0] = f2bf(f.x); o[1] = f2bf(f.y); o[2] = f2bf(f.z); o[3] = f2bf(f.w);
            reinterpret_cast<bf16x4*>(v_bf)[i] = o;
        }
    } else if (sec == 1 || sec == 2) {    // wq / wk transpose + split
        const float* w  = (sec == 1) ? wq : wk;
        bf16* whi = (sec == 1) ? wqT_hi : wkT_hi;
        bf16* wlo = (sec == 1) ? wqT_lo : wkT_lo;
        for (int i = tid; i < H_ * DK_ * D_; i += nthr) {
            const int k = i & (D_ - 1);
            const int c = (i >> 10) & (DK_ - 1);
            const int h = i >> 16;
            const float f = w[((size_t)h * D_ + k) * DK_ + c];
            const bf16 hi = f2bf(f);
            whi[i] = hi;
            wlo[i] = f2bf(f - bf2f(hi));
        }
    } else if (sec == 3) {                // wv transpose (single bf16)
        for (int i = tid; i < H_ * DK_ * D_; i += nthr) {
            const int k = i & (D_ - 1);
            const int d = (i >> 10) & (DK_ - 1);
            const int h = i >> 16;
            wvT[i] = f2bf(wv[((size_t)h * D_ + k) * DK_ + d]);
        }
    } else {                              // wo transpose (single bf16)
        for (int i = tid; i < D_ * D_; i += nthr) {
            const int k = i & (D_ - 1);
            const int c = i >> 10;
            woT[i] = f2bf(wo[(size_t)k * D_ + c]);
        }
    }
}

// ---------------------------------------------------------------------------
// Kernel 1: Q/K projection, split-bf16 (3 MFMAs), LDS-staged A-tile.
// grid (8192/128, 2*H). Per block: 128 rows x 64 cols (one head), BK=64.
// A f32 loads are coalesced (8 thr x 32B per row), converted to hi/lo bf16,
// ds_written XOR-swizzled; fragments then read as ds_read_b128.
// Q pre-scaled by 1/sqrt(dk)=0.125.
// ---------------------------------------------------------------------------
__global__ __launch_bounds__(256, 4) void proj_qk_kernel(
    const float* __restrict__ q, const float* __restrict__ k,
    const bf16* __restrict__ wqT_hi, const bf16* __restrict__ wqT_lo,
    const bf16* __restrict__ wkT_hi, const bf16* __restrict__ wkT_lo,
    bf16* __restrict__ qh_hi, bf16* __restrict__ qh_lo,
    bf16* __restrict__ kh_hi, bf16* __restrict__ kh_lo) {
    __shared__ __align__(16) unsigned char alds[32768];  // hi @0, lo @16K
    const int mat = blockIdx.y >> 4;       // 0=q, 1=k
    const int h   = blockIdx.y & 15;
    const float* x      = mat ? k      : q;
    const bf16* wT_hi   = mat ? wkT_hi : wqT_hi;
    const bf16* wT_lo   = mat ? wkT_lo : wqT_lo;
    bf16* out_hi        = mat ? kh_hi  : qh_hi;
    bf16* out_lo        = mat ? kh_lo  : qh_lo;
    const float scale   = mat ? 1.0f : 0.125f;

    const int m0 = blockIdx.x * 128;
    const int t  = threadIdx.x;
    const int w  = t >> 6;
    const int l  = t & 63;
    const int lr = l & 15, lg = l >> 4;
    const int srow = t >> 3;          // staging row 0..31 (+it*32)
    const int scol = (t & 7) * 8;     // staging float col

    f32x4 acc[2][4] = {};
    for (int kk = 0; kk < D_; kk += 64) {
        // coalesced staging loads (issued before barrier: overlap prev compute)
        float4 st[4][2];
#pragma unroll
        for (int it = 0; it < 4; ++it) {
            const float4* ap = reinterpret_cast<const float4*>(
                x + (size_t)(m0 + srow + it * 32) * D_ + kk + scol);
            st[it][0] = ap[0]; st[it][1] = ap[1];
        }
        __syncthreads();   // prev compute done before LDS overwrite
#pragma unroll
        for (int it = 0; it < 4; ++it) {
            const int r = srow + it * 32;
            const float ff[8] = {st[it][0].x, st[it][0].y, st[it][0].z, st[it][0].w,
                                 st[it][1].x, st[it][1].y, st[it][1].z, st[it][1].w};
            bf16x8 hi8, lo8;
#pragma unroll
            for (int j = 0; j < 8; ++j) {
                const float f   = ff[j] * scale;
                const bf16 hiv = f2bf(f);
                hi8[j] = hiv;
                lo8[j] = f2bf(f - bf2f(hiv));
            }
            const int byte = r * 128 + ((scol * 2) ^ ((r & 7) << 4));
            *reinterpret_cast<bf16x8*>(alds + byte)         = hi8;
            *reinterpret_cast<bf16x8*>(alds + 16384 + byte) = lo8;
        }
        __syncthreads();
#pragma unroll
        for (int ks = 0; ks < 2; ++ks) {
            bf16x8 a_hi[2], a_lo[2];
#pragma unroll
            for (int mf = 0; mf < 2; ++mf) {
                const int row  = w * 32 + mf * 16 + lr;
                const int byte = row * 128 + ((ks * 64 + lg * 16) ^ ((row & 7) << 4));
                a_hi[mf] = *reinterpret_cast<const bf16x8*>(alds + byte);
                a_lo[mf] = *reinterpret_cast<const bf16x8*>(alds + 16384 + byte);
            }
#pragma unroll
            for (int nf = 0; nf < 4; ++nf) {
                const size_t boff =
                    ((size_t)h * DK_ + nf * 16 + lr) * D_ + kk + ks * 32 + lg * 8;
                const bf16x8 b_hi = *reinterpret_cast<const bf16x8*>(wT_hi + boff);
                const bf16x8 b_lo = *reinterpret_cast<const bf16x8*>(wT_lo + boff);
#pragma unroll
                for (int mf = 0; mf < 2; ++mf) {
                    acc[mf][nf] = mfma16(a_hi[mf], b_hi, acc[mf][nf]);
                    acc[mf][nf] = mfma16(a_hi[mf], b_lo, acc[mf][nf]);
                    acc[mf][nf] = mfma16(a_lo[mf], b_hi, acc[mf][nf]);
                }
            }
        }
    }
#pragma unroll
    for (int mf = 0; mf < 2; ++mf)
#pragma unroll
        for (int nf = 0; nf < 4; ++nf)
#pragma unroll
            for (int i = 0; i < 4; ++i) {
                const int m = m0 + w * 32 + mf * 16 + lg * 4 + i;
                const int b = m >> 11, n = m & (N_ - 1);
                const int c = nf * 16 + lr;
                const float val = acc[mf][nf][i];
                const bf16 hi = f2bf(val);
                const size_t oidx = (((size_t)(b * H_ + h)) * N_ + n) * DK_ + c;
                out_hi[oidx] = hi;
                out_lo[oidx] = f2bf(val - bf2f(hi));
            }
}

// ---------------------------------------------------------------------------
// Kernel 2: V projection with swapped operands -> vhT [B,H,dv,N]. (unchanged)
// ---------------------------------------------------------------------------
__global__ __launch_bounds__(256) void proj_v_kernel(
    const bf16* __restrict__ v_bf, const bf16* __restrict__ wvT,
    bf16* __restrict__ vhT) {
    const int bh = blockIdx.y;
    const int b = bh >> 4, h = bh & 15;
    const int s0 = blockIdx.x * 64;
    const int w = threadIdx.x >> 6, l = threadIdx.x & 63;
    const int lr = l & 15, lg = l >> 4;

    f32x4 acc[4] = {};
    for (int kk = 0; kk < D_; kk += 32) {
        const bf16x8 a = *reinterpret_cast<const bf16x8*>(
            wvT + ((size_t)h * DK_ + w * 16 + lr) * D_ + kk + lg * 8);
#pragma unroll
        for (int nf = 0; nf < 4; ++nf) {
            const bf16x8 bb = *reinterpret_cast<const bf16x8*>(
                v_bf + ((size_t)b * N_ + s0 + nf * 16 + lr) * D_ + kk + lg * 8);
            acc[nf] = mfma16(a, bb, acc[nf]);
        }
    }
#pragma unroll
    for (int nf = 0; nf < 4; ++nf)
#pragma unroll
        for (int i = 0; i < 4; ++i) {
            const int d = w * 16 + lg * 4 + i;
            const int s = s0 + nf * 16 + lr;
            vhT[(((size_t)(b * H_ + h)) * DK_ + d) * N_ + s] = f2bf(acc[nf][i]);
        }
}

// ---------------------------------------------------------------------------
// Kernel 3: causal flash attention, load-balanced. (unchanged from R3)
// ---------------------------------------------------------------------------
__global__ __launch_bounds__(256, 4) void attn_kernel(
    const bf16* __restrict__ qh_hi, const bf16* __restrict__ qh_lo,
    const bf16* __restrict__ kh_hi, const bf16* __restrict__ kh_lo,
    const bf16* __restrict__ vhT, bf16* __restrict__ o_flat) {
    __shared__ __align__(16) unsigned char plds[4 * 2048];
    const int bid  = blockIdx.x;
    const int wgid = (bid & 7) * 128 + (bid >> 3);
    const int bh   = wgid >> 4;   // 0..63  (b*16+h)
    const int pr   = wgid & 15;   // pair index 0..15
    const int b = bh >> 4, h = bh & 15;
    const int w = threadIdx.x >> 6, l = threadIdx.x & 63;
    const int lr = l & 15, lg = l >> 4;
    unsigned char* myp = plds + w * 2048;
    const size_t hb = (size_t)(b * H_ + h);

#pragma unroll
    for (int phase = 0; phase < 2; ++phase) {
        const int qt = phase ? (31 - pr) : pr;
        const int q0 = qt * 64 + w * 16;

        bf16x8 qf_hi[2], qf_lo[2];
#pragma unroll
        for (int ks = 0; ks < 2; ++ks) {
            const size_t off = (hb * N_ + q0 + lr) * DK_ + ks * 32 + lg * 8;
            qf_hi[ks] = *reinterpret_cast<const bf16x8*>(qh_hi + off);
            qf_lo[ks] = *reinterpret_cast<const bf16x8*>(qh_lo + off);
        }

        f32x4 m_run, l_run, o_acc[4];
#pragma unroll
        for (int i = 0; i < 4; ++i) { m_run[i] = -3e38f; l_run[i] = 0.f; }
#pragma unroll
        for (int dt = 0; dt < 4; ++dt) o_acc[dt] = f32x4{0.f, 0.f, 0.f, 0.f};

        const int nt = qt + 1;
        for (int t = 0; t < nt; ++t) {
            const int s0 = t * 64;
            f32x4 sacc[4];
#pragma unroll
            for (int f = 0; f < 4; ++f) {
                sacc[f] = f32x4{0.f, 0.f, 0.f, 0.f};
#pragma unroll
                for (int ks = 0; ks < 2; ++ks) {
                    const size_t off = (hb * N_ + s0 + f * 16 + lr) * DK_ + ks * 32 + lg * 8;
                    const bf16x8 k_hi = *reinterpret_cast<const bf16x8*>(kh_hi + off);
                    const bf16x8 k_lo = *reinterpret_cast<const bf16x8*>(kh_lo + off);
                    sacc[f] = mfma16(qf_hi[ks], k_hi, sacc[f]);
                    sacc[f] = mfma16(qf_hi[ks], k_lo, sacc[f]);
                    sacc[f] = mfma16(qf_lo[ks], k_hi, sacc[f]);
                }
            }
            bf16x8 vb[4][2];
#pragma unroll
            for (int dt = 0; dt < 4; ++dt)
#pragma unroll
                for (int ks = 0; ks < 2; ++ks)
                    vb[dt][ks] = *reinterpret_cast<const bf16x8*>(
                        vhT + (hb * DK_ + dt * 16 + lr) * N_ + s0 + ks * 32 + lg * 8);

            if (t == nt - 1) {  // diagonal tile: mask s > q
#pragma unroll
                for (int f = 0; f < 4; ++f) {
                    const int s = s0 + f * 16 + lr;
#pragma unroll
                    for (int i = 0; i < 4; ++i) {
                        const int qq = q0 + lg * 4 + i;
                        if (s > qq) sacc[f][i] = -1e9f;
                    }
                }
            }
            f32x4 tmax;
#pragma unroll
            for (int i = 0; i < 4; ++i)
                tmax[i] = fmaxf(fmaxf(sacc[0][i], sacc[1][i]), fmaxf(sacc[2][i], sacc[3][i]));
#pragma unroll
            for (int off = 1; off < 16; off <<= 1)
#pragma unroll
                for (int i = 0; i < 4; ++i)
                    tmax[i] = fmaxf(tmax[i], __shfl_xor(tmax[i], off));
            f32x4 m_new, escale;
#pragma unroll
            for (int i = 0; i < 4; ++i) {
                m_new[i]  = fmaxf(m_run[i], tmax[i]);
                escale[i] = __expf(m_run[i] - m_new[i]);
            }
            float p[4][4];
            f32x4 rsum;
#pragma unroll
            for (int i = 0; i < 4; ++i) rsum[i] = 0.f;
#pragma unroll
            for (int f = 0; f < 4; ++f)
#pragma unroll
                for (int i = 0; i < 4; ++i) {
                    p[f][i] = __expf(sacc[f][i] - m_new[i]);
                    rsum[i] += p[f][i];
                }
#pragma unroll
            for (int off = 1; off < 16; off <<= 1)
#pragma unroll
                for (int i = 0; i < 4; ++i) rsum[i] += __shfl_xor(rsum[i], off);
#pragma unroll
            for (int i = 0; i < 4; ++i) {
                l_run[i] = l_run[i] * escale[i] + rsum[i];
                m_run[i] = m_new[i];
            }
#pragma unroll
            for (int dt = 0; dt < 4; ++dt)
#pragma unroll
                for (int i = 0; i < 4; ++i) o_acc[dt][i] *= escale[i];
#pragma unroll
            for (int f = 0; f < 4; ++f)
#pragma unroll
                for (int i = 0; i < 4; ++i) {
                    const int row = lg * 4 + i, col = f * 16 + lr;
                    const int byte = (row * 128 + col * 2) ^ ((row & 7) << 4);
                    *reinterpret_cast<bf16*>(myp + byte) = f2bf(p[f][i]);
                }
            bf16x8 pa[2];
#pragma unroll
            for (int ks = 0; ks < 2; ++ks) {
                const int byte = (lr * 128 + ks * 64 + lg * 16) ^ ((lr & 7) << 4);
                pa[ks] = *reinterpret_cast<const bf16x8*>(myp + byte);
            }
#pragma unroll
            for (int dt = 0; dt < 4; ++dt)
#pragma unroll
                for (int ks = 0; ks < 2; ++ks)
                    o_acc[dt] = mfma16(pa[ks], vb[dt][ks], o_acc[dt]);
        }
#pragma unroll
        for (int dt = 0; dt < 4; ++dt)
#pragma unroll
            for (int i = 0; i < 4; ++i) {
                const int qq = q0 + lg * 4 + i;
                const float val = o_acc[dt][i] / l_run[i];
                o_flat[((size_t)b * N_ + qq) * (H_ * DK_) + h * DK_ + dt * 16 + lr] =
                    f2bf(val);
            }
    }
}

// ---------------------------------------------------------------------------
// Kernel 4: output projection with LDS-staged A-tile. grid (64, 16), BK=64.
// ---------------------------------------------------------------------------
__global__ __launch_bounds__(256, 4) void outproj_kernel(
    const bf16* __restrict__ o_flat, const bf16* __restrict__ woT,
    float* __restrict__ out) {
    __shared__ __align__(16) unsigned char alds[16384];
    const int m0   = blockIdx.x * 128;
    const int col0 = blockIdx.y * 64;
    const int t = threadIdx.x;
    const int w = t >> 6, l = t & 63;
    const int lr = l & 15, lg = l >> 4;
    const int srow = t >> 3;           // 0..31 (+it*32)
    const int scb  = (t & 7) * 16;     // staging byte col (row = 128B)

    f32x4 acc[2][4] = {};
    for (int kk = 0; kk < D_; kk += 64) {
        bf16x8 st[4];
#pragma unroll
        for (int it = 0; it < 4; ++it)
            st[it] = *reinterpret_cast<const bf16x8*>(
                o_flat + (size_t)(m0 + srow + it * 32) * D_ + kk + (t & 7) * 8);
        __syncthreads();
#pragma unroll
        for (int it = 0; it < 4; ++it) {
            const int r = srow + it * 32;
            *reinterpret_cast<bf16x8*>(alds + r * 128 + (scb ^ ((r & 7) << 4))) = st[it];
        }
        __syncthreads();
#pragma unroll
        for (int ks = 0; ks < 2; ++ks) {
            bf16x8 a[2];
#pragma unroll
            for (int mf = 0; mf < 2; ++mf) {
                const int row = w * 32 + mf * 16 + lr;
                a[mf] = *reinterpret_cast<const bf16x8*>(
                    alds + row * 128 + ((ks * 64 + lg * 16) ^ ((row & 7) << 4)));
            }
#pragma unroll
            for (int nf = 0; nf < 4; ++nf) {
                const bf16x8 bb = *reinterpret_cast<const bf16x8*>(
                    woT + ((size_t)col0 + nf * 16 + lr) * D_ + kk + ks * 32 + lg * 8);
#pragma unroll
                for (int mf = 0; mf < 2; ++mf)
                    acc[mf][nf] = mfma16(a[mf], bb, acc[mf][nf]);
            }
        }
    }
#pragma unroll
    for (int mf = 0; mf < 2; ++mf)
#pragma unroll
        for (int nf = 0; nf < 4; ++nf)
#pragma unroll
            for (int i = 0; i < 4; ++i) {
                const int m = m0 + w * 32 + mf * 16 + lg * 4 + i;
                out[(size_t)m * D_ + col0 + nf * 16 + lr] = acc[mf][nf][i];
            }
}

// ---------------------------------------------------------------------------
extern "C" void kernel_launch(void* const* d_in, const int* in_sizes, int n_in,
                              void* d_out, int out_size, void* d_ws, size_t ws_size,
                              hipStream_t stream) {
    const float* q  = (const float*)d_in[0];
    const float* k  = (const float*)d_in[1];
    const float* v  = (const float*)d_in[2];
    const float* wq = (const float*)d_in[3];
    const float* wk = (const float*)d_in[4];
    const float* wv = (const float*)d_in[5];
    const float* wo = (const float*)d_in[6];
    float* out = (float*)d_out;

    char* p = (char*)d_ws;
    auto alloc = [&](size_t elems) {
        bf16* r = (bf16*)p;
        p += ((elems * 2 + 255) / 256) * 256;
        return r;
    };
    bf16* v_bf   = alloc((size_t)B_ * N_ * D_);
    bf16* wqT_hi = alloc((size_t)H_ * DK_ * D_);
    bf16* wqT_lo = alloc((size_t)H_ * DK_ * D_);
    bf16* wkT_hi = alloc((size_t)H_ * DK_ * D_);
    bf16* wkT_lo = alloc((size_t)H_ * DK_ * D_);
    bf16* wvT    = alloc((size_t)H_ * DK_ * D_);
    bf16* woT    = alloc((size_t)D_ * D_);
    bf16* qh_hi  = alloc((size_t)B_ * H_ * N_ * DK_);
    bf16* qh_lo  = alloc((size_t)B_ * H_ * N_ * DK_);
    bf16* kh_hi  = alloc((size_t)B_ * H_ * N_ * DK_);
    bf16* kh_lo  = alloc((size_t)B_ * H_ * N_ * DK_);
    bf16* vhT    = alloc((size_t)B_ * H_ * DK_ * N_);
    bf16* o_flat = alloc((size_t)B_ * N_ * H_ * DK_);

    if ((size_t)(p - (char*)d_ws) > ws_size) return;  // ws too small: bail

    prep_kernel<<<dim3(1024, 5), 256, 0, stream>>>(v, wq, wk, wv, wo, v_bf,
                                                   wqT_hi, wqT_lo, wkT_hi, wkT_lo, wvT, woT);
    proj_qk_kernel<<<dim3(64, 32), 256, 0, stream>>>(q, k, wqT_hi, wqT_lo, wkT_hi, wkT_lo,
                                                     qh_hi, qh_lo, kh_hi, kh_lo);
    proj_v_kernel<<<dim3(32, 64), 256, 0, stream>>>(v_bf, wvT, vhT);
    attn_kernel<<<1024, 256, 0, stream>>>(qh_hi, qh_lo, kh_hi, kh_lo, vhT, o_flat);
    outproj_kernel<<<dim3(64, 16), 256, 0, stream>>>(o_flat, woT, out);
}

// Round 6
// 874.171 us; speedup vs baseline: 1.6013x; 1.1402x over previous
//
#include <hip/hip_runtime.h>

// ---------------------------------------------------------------------------
// Fused multi-head attention (B=4, N=2048, D=1024, H=16, dk=dv=64, causal)
// bf16 MFMA; Q/K path split-bf16 (hi/lo, 3 MFMAs) for ~fp32 logits.
// R6: (a) attn: row-sum via ones-column MFMA (kills sum butterfly), row-max
// via DPP row_ror folds (VALU latency) instead of shfl/ds_bpermute;
// (b) proj_qk: 128x256 tile (4 heads/block, wave=head) -> A re-read 16x->4x,
// disjoint per-wave B loads.
// ---------------------------------------------------------------------------

typedef short bf16;  // bf16 stored as raw bits
typedef short bf16x8 __attribute__((ext_vector_type(8)));
typedef short bf16x4 __attribute__((ext_vector_type(4)));
typedef float f32x4  __attribute__((ext_vector_type(4)));

constexpr int B_ = 4, N_ = 2048, D_ = 1024, H_ = 16, DK_ = 64;

static __device__ __forceinline__ bf16 f2bf(float f) {  // RNE float->bf16
    union { float f; unsigned u; } x; x.f = f;
    const unsigned r = x.u + 0x7FFFu + ((x.u >> 16) & 1u);
    return (bf16)(r >> 16);
}
static __device__ __forceinline__ float bf2f(bf16 s) {
    union { unsigned u; float f; } x; x.u = ((unsigned)(unsigned short)s) << 16;
    return x.f;
}

static __device__ __forceinline__ f32x4 mfma16(bf16x8 a, bf16x8 b, f32x4 c) {
    return __builtin_amdgcn_mfma_f32_16x16x32_bf16(a, b, c, 0, 0, 0);
}

// DPP row-rotate move (16-lane row), VALU latency — for cross-lane max.
template <int CTRL>
static __device__ __forceinline__ float dpp_mov(float x) {
    return __int_as_float(__builtin_amdgcn_update_dpp(
        __float_as_int(x), __float_as_int(x), CTRL, 0xF, 0xF, false));
}
static __device__ __forceinline__ float rowmax16(float x) {
    x = fmaxf(x, dpp_mov<0x128>(x));  // ror:8
    x = fmaxf(x, dpp_mov<0x124>(x));  // ror:4
    x = fmaxf(x, dpp_mov<0x122>(x));  // ror:2
    x = fmaxf(x, dpp_mov<0x121>(x));  // ror:1
    return x;
}

// ---------------------------------------------------------------------------
// Kernel 0: prep — cast v to bf16; transpose (+split) weights. (unchanged)
// ---------------------------------------------------------------------------
__global__ __launch_bounds__(256) void prep_kernel(
    const float* __restrict__ v,  const float* __restrict__ wq,
    const float* __restrict__ wk, const float* __restrict__ wv,
    const float* __restrict__ wo,
    bf16* __restrict__ v_bf,
    bf16* __restrict__ wqT_hi, bf16* __restrict__ wqT_lo,
    bf16* __restrict__ wkT_hi, bf16* __restrict__ wkT_lo,
    bf16* __restrict__ wvT, bf16* __restrict__ woT) {
    const int sec  = blockIdx.y;
    const int tid  = blockIdx.x * blockDim.x + threadIdx.x;
    const int nthr = gridDim.x * blockDim.x;
    if (sec == 0) {                       // v -> bf16, 4-wide
        const int n4 = (B_ * N_ * D_) / 4;
        for (int i = tid; i < n4; i += nthr) {
            const float4 f = reinterpret_cast<const float4*>(v)[i];
            bf16x4 o;
            o[0] = f2bf(f.x); o[1] = f2bf(f.y); o[2] = f2bf(f.z); o[3] = f2bf(f.w);
            reinterpret_cast<bf16x4*>(v_bf)[i] = o;
        }
    } else if (sec == 1 || sec == 2) {    // wq / wk transpose + split
        const float* w  = (sec == 1) ? wq : wk;
        bf16* whi = (sec == 1) ? wqT_hi : wkT_hi;
        bf16* wlo = (sec == 1) ? wqT_lo : wkT_lo;
        for (int i = tid; i < H_ * DK_ * D_; i += nthr) {
            const int k = i & (D_ - 1);
            const int c = (i >> 10) & (DK_ - 1);
            const int h = i >> 16;
            const float f = w[((size_t)h * D_ + k) * DK_ + c];
            const bf16 hi = f2bf(f);
            whi[i] = hi;
            wlo[i] = f2bf(f - bf2f(hi));
        }
    } else if (sec == 3) {                // wv transpose (single bf16)
        for (int i = tid; i < H_ * DK_ * D_; i += nthr) {
            const int k = i & (D_ - 1);
            const int d = (i >> 10) & (DK_ - 1);
            const int h = i >> 16;
            wvT[i] = f2bf(wv[((size_t)h * D_ + k) * DK_ + d]);
        }
    } else {                              // wo transpose (single bf16)
        for (int i = tid; i < D_ * D_; i += nthr) {
            const int k = i & (D_ - 1);
            const int c = i >> 10;
            woT[i] = f2bf(wo[(size_t)k * D_ + c]);
        }
    }
}

// ---------------------------------------------------------------------------
// Kernel 1: Q/K projection, split-bf16, LDS-staged A, 128x256 tile.
// grid (64, 8): y = mat*4 + colgroup. Block: 128 rows x 256 cols (4 heads).
// Wave w handles head cg*4+w (its 64 cols), all 128 rows: acc[8][4].
// A staged once per kk (hi/lo, XOR-swizzled); B loads disjoint per wave.
// Q pre-scaled by 1/sqrt(dk)=0.125.
// ---------------------------------------------------------------------------
__global__ __launch_bounds__(256, 2) void proj_qk_kernel(
    const float* __restrict__ q, const float* __restrict__ k,
    const bf16* __restrict__ wqT_hi, const bf16* __restrict__ wqT_lo,
    const bf16* __restrict__ wkT_hi, const bf16* __restrict__ wkT_lo,
    bf16* __restrict__ qh_hi, bf16* __restrict__ qh_lo,
    bf16* __restrict__ kh_hi, bf16* __restrict__ kh_lo) {
    __shared__ __align__(16) unsigned char alds[32768];  // hi @0, lo @16K
    const int mat = blockIdx.y >> 2;       // 0=q, 1=k
    const int cg  = blockIdx.y & 3;        // col group (4 heads)
    const float* x      = mat ? k      : q;
    const bf16* wT_hi   = mat ? wkT_hi : wqT_hi;
    const bf16* wT_lo   = mat ? wkT_lo : wqT_lo;
    bf16* out_hi        = mat ? kh_hi  : qh_hi;
    bf16* out_lo        = mat ? kh_lo  : qh_lo;
    const float scale   = mat ? 1.0f : 0.125f;

    const int m0 = blockIdx.x * 128;
    const int t  = threadIdx.x;
    const int w  = t >> 6;
    const int l  = t & 63;
    const int lr = l & 15, lg = l >> 4;
    const int srow = t >> 3;          // staging row 0..31 (+it*32)
    const int scol = (t & 7) * 8;     // staging float col

    f32x4 acc[8][4] = {};   // mf (16-row slabs) x nf (16-col slabs of this head)
    for (int kk = 0; kk < D_; kk += 64) {
        float4 st[4][2];
#pragma unroll
        for (int it = 0; it < 4; ++it) {
            const float4* ap = reinterpret_cast<const float4*>(
                x + (size_t)(m0 + srow + it * 32) * D_ + kk + scol);
            st[it][0] = ap[0]; st[it][1] = ap[1];
        }
        __syncthreads();   // prev compute done before LDS overwrite
#pragma unroll
        for (int it = 0; it < 4; ++it) {
            const int r = srow + it * 32;
            const float ff[8] = {st[it][0].x, st[it][0].y, st[it][0].z, st[it][0].w,
                                 st[it][1].x, st[it][1].y, st[it][1].z, st[it][1].w};
            bf16x8 hi8, lo8;
#pragma unroll
            for (int j = 0; j < 8; ++j) {
                const float f   = ff[j] * scale;
                const bf16 hiv = f2bf(f);
                hi8[j] = hiv;
                lo8[j] = f2bf(f - bf2f(hiv));
            }
            const int byte = r * 128 + ((scol * 2) ^ ((r & 7) << 4));
            *reinterpret_cast<bf16x8*>(alds + byte)         = hi8;
            *reinterpret_cast<bf16x8*>(alds + 16384 + byte) = lo8;
        }
        __syncthreads();
#pragma unroll
        for (int ks = 0; ks < 2; ++ks) {
            bf16x8 a_hi[8], a_lo[8];
#pragma unroll
            for (int mf = 0; mf < 8; ++mf) {
                const int row  = mf * 16 + lr;
                const int byte = row * 128 + ((ks * 64 + lg * 16) ^ ((row & 7) << 4));
                a_hi[mf] = *reinterpret_cast<const bf16x8*>(alds + byte);
                a_lo[mf] = *reinterpret_cast<const bf16x8*>(alds + 16384 + byte);
            }
#pragma unroll
            for (int nf = 0; nf < 4; ++nf) {
                const int c = cg * 256 + w * 64 + nf * 16 + lr;  // global out col
                const size_t boff = (size_t)c * D_ + kk + ks * 32 + lg * 8;
                const bf16x8 b_hi = *reinterpret_cast<const bf16x8*>(wT_hi + boff);
                const bf16x8 b_lo = *reinterpret_cast<const bf16x8*>(wT_lo + boff);
#pragma unroll
                for (int mf = 0; mf < 8; ++mf) {
                    acc[mf][nf] = mfma16(a_hi[mf], b_hi, acc[mf][nf]);
                    acc[mf][nf] = mfma16(a_hi[mf], b_lo, acc[mf][nf]);
                    acc[mf][nf] = mfma16(a_lo[mf], b_hi, acc[mf][nf]);
                }
            }
        }
    }
    const int h = cg * 4 + w;   // wave's head
#pragma unroll
    for (int mf = 0; mf < 8; ++mf)
#pragma unroll
        for (int nf = 0; nf < 4; ++nf)
#pragma unroll
            for (int i = 0; i < 4; ++i) {
                const int m = m0 + mf * 16 + lg * 4 + i;
                const int b = m >> 11, n = m & (N_ - 1);
                const int cc = nf * 16 + lr;
                const float val = acc[mf][nf][i];
                const bf16 hi = f2bf(val);
                const size_t oidx = (((size_t)(b * H_ + h)) * N_ + n) * DK_ + cc;
                out_hi[oidx] = hi;
                out_lo[oidx] = f2bf(val - bf2f(hi));
            }
}

// ---------------------------------------------------------------------------
// Kernel 2: V projection with swapped operands -> vhT [B,H,dv,N]. (unchanged)
// ---------------------------------------------------------------------------
__global__ __launch_bounds__(256) void proj_v_kernel(
    const bf16* __restrict__ v_bf, const bf16* __restrict__ wvT,
    bf16* __restrict__ vhT) {
    const int bh = blockIdx.y;
    const int b = bh >> 4, h = bh & 15;
    const int s0 = blockIdx.x * 64;
    const int w = threadIdx.x >> 6, l = threadIdx.x & 63;
    const int lr = l & 15, lg = l >> 4;

    f32x4 acc[4] = {};
    for (int kk = 0; kk < D_; kk += 32) {
        const bf16x8 a = *reinterpret_cast<const bf16x8*>(
            wvT + ((size_t)h * DK_ + w * 16 + lr) * D_ + kk + lg * 8);
#pragma unroll
        for (int nf = 0; nf < 4; ++nf) {
            const bf16x8 bb = *reinterpret_cast<const bf16x8*>(
                v_bf + ((size_t)b * N_ + s0 + nf * 16 + lr) * D_ + kk + lg * 8);
            acc[nf] = mfma16(a, bb, acc[nf]);
        }
    }
#pragma unroll
    for (int nf = 0; nf < 4; ++nf)
#pragma unroll
        for (int i = 0; i < 4; ++i) {
            const int d = w * 16 + lg * 4 + i;
            const int s = s0 + nf * 16 + lr;
            vhT[(((size_t)(b * H_ + h)) * DK_ + d) * N_ + s] = f2bf(acc[nf][i]);
        }
}

// ---------------------------------------------------------------------------
// Kernel 3: causal flash attention, load-balanced pairs (p, 31-p).
// R6: row-max via DPP ror folds; row-sum (l) via ones-column MFMA
// accumulated online exactly like o_acc. No shfl/ds_bpermute anywhere.
// ---------------------------------------------------------------------------
__global__ __launch_bounds__(256, 4) void attn_kernel(
    const bf16* __restrict__ qh_hi, const bf16* __restrict__ qh_lo,
    const bf16* __restrict__ kh_hi, const bf16* __restrict__ kh_lo,
    const bf16* __restrict__ vhT, bf16* __restrict__ o_flat) {
    __shared__ __align__(16) unsigned char plds[4 * 2048];
    const int bid  = blockIdx.x;
    const int wgid = (bid & 7) * 128 + (bid >> 3);
    const int bh   = wgid >> 4;   // 0..63  (b*16+h)
    const int pr   = wgid & 15;   // pair index 0..15
    const int b = bh >> 4, h = bh & 15;
    const int w = threadIdx.x >> 6, l = threadIdx.x & 63;
    const int lr = l & 15, lg = l >> 4;
    unsigned char* myp = plds + w * 2048;
    const size_t hb = (size_t)(b * H_ + h);

    bf16x8 ones;
#pragma unroll
    for (int j = 0; j < 8; ++j) ones[j] = (bf16)0x3F80;  // 1.0bf16

#pragma unroll
    for (int phase = 0; phase < 2; ++phase) {
        const int qt = phase ? (31 - pr) : pr;
        const int q0 = qt * 64 + w * 16;

        bf16x8 qf_hi[2], qf_lo[2];
#pragma unroll
        for (int ks = 0; ks < 2; ++ks) {
            const size_t off = (hb * N_ + q0 + lr) * DK_ + ks * 32 + lg * 8;
            qf_hi[ks] = *reinterpret_cast<const bf16x8*>(qh_hi + off);
            qf_lo[ks] = *reinterpret_cast<const bf16x8*>(qh_lo + off);
        }

        f32x4 m_run, l_acc, o_acc[4];
#pragma unroll
        for (int i = 0; i < 4; ++i) { m_run[i] = -3e38f; l_acc[i] = 0.f; }
#pragma unroll
        for (int dt = 0; dt < 4; ++dt) o_acc[dt] = f32x4{0.f, 0.f, 0.f, 0.f};

        const int nt = qt + 1;
        for (int t = 0; t < nt; ++t) {
            const int s0 = t * 64;
            f32x4 sacc[4];
#pragma unroll
            for (int f = 0; f < 4; ++f) {
                sacc[f] = f32x4{0.f, 0.f, 0.f, 0.f};
#pragma unroll
                for (int ks = 0; ks < 2; ++ks) {
                    const size_t off = (hb * N_ + s0 + f * 16 + lr) * DK_ + ks * 32 + lg * 8;
                    const bf16x8 k_hi = *reinterpret_cast<const bf16x8*>(kh_hi + off);
                    const bf16x8 k_lo = *reinterpret_cast<const bf16x8*>(kh_lo + off);
                    sacc[f] = mfma16(qf_hi[ks], k_hi, sacc[f]);
                    sacc[f] = mfma16(qf_hi[ks], k_lo, sacc[f]);
                    sacc[f] = mfma16(qf_lo[ks], k_hi, sacc[f]);
                }
            }
            // V loads hoisted: overlap the max fold + exp
            bf16x8 vb[4][2];
#pragma unroll
            for (int dt = 0; dt < 4; ++dt)
#pragma unroll
                for (int ks = 0; ks < 2; ++ks)
                    vb[dt][ks] = *reinterpret_cast<const bf16x8*>(
                        vhT + (hb * DK_ + dt * 16 + lr) * N_ + s0 + ks * 32 + lg * 8);

            if (t == nt - 1) {  // diagonal tile: mask s > q
#pragma unroll
                for (int f = 0; f < 4; ++f) {
                    const int s = s0 + f * 16 + lr;
#pragma unroll
                    for (int i = 0; i < 4; ++i) {
                        const int qq = q0 + lg * 4 + i;
                        if (s > qq) sacc[f][i] = -1e9f;
                    }
                }
            }
            // row max over 64 s: in-lane over 4 frags, then DPP 16-lane fold
            f32x4 m_new, escale;
#pragma unroll
            for (int i = 0; i < 4; ++i) {
                float tm = fmaxf(fmaxf(sacc[0][i], sacc[1][i]),
                                 fmaxf(sacc[2][i], sacc[3][i]));
                tm = rowmax16(tm);
                m_new[i]  = fmaxf(m_run[i], tm);
                escale[i] = __expf(m_run[i] - m_new[i]);
                m_run[i]  = m_new[i];
            }
            // P = exp(S - m), write to swizzled LDS (C-layout -> A-layout)
#pragma unroll
            for (int f = 0; f < 4; ++f)
#pragma unroll
                for (int i = 0; i < 4; ++i) {
                    const float p = __expf(sacc[f][i] - m_new[i]);
                    const int row = lg * 4 + i, col = f * 16 + lr;
                    const int byte = (row * 128 + col * 2) ^ ((row & 7) << 4);
                    *reinterpret_cast<bf16*>(myp + byte) = f2bf(p);
                }
            // rescale accumulators (l rides along as the ones-column)
#pragma unroll
            for (int i = 0; i < 4; ++i) l_acc[i] *= escale[i];
#pragma unroll
            for (int dt = 0; dt < 4; ++dt)
#pragma unroll
                for (int i = 0; i < 4; ++i) o_acc[dt][i] *= escale[i];
            bf16x8 pa[2];
#pragma unroll
            for (int ks = 0; ks < 2; ++ks) {
                const int byte = (lr * 128 + ks * 64 + lg * 16) ^ ((lr & 7) << 4);
                pa[ks] = *reinterpret_cast<const bf16x8*>(myp + byte);
            }
#pragma unroll
            for (int dt = 0; dt < 4; ++dt)
#pragma unroll
                for (int ks = 0; ks < 2; ++ks)
                    o_acc[dt] = mfma16(pa[ks], vb[dt][ks], o_acc[dt]);
#pragma unroll
            for (int ks = 0; ks < 2; ++ks)       // row-sum column: V = ones
                l_acc = mfma16(pa[ks], ones, l_acc);
        }
#pragma unroll
        for (int dt = 0; dt < 4; ++dt)
#pragma unroll
            for (int i = 0; i < 4; ++i) {
                const int qq = q0 + lg * 4 + i;
                const float val = o_acc[dt][i] / l_acc[i];
                o_flat[((size_t)b * N_ + qq) * (H_ * DK_) + h * DK_ + dt * 16 + lr] =
                    f2bf(val);
            }
    }
}

// ---------------------------------------------------------------------------
// Kernel 4: output projection with LDS-staged A-tile. (unchanged from R4)
// ---------------------------------------------------------------------------
__global__ __launch_bounds__(256, 4) void outproj_kernel(
    const bf16* __restrict__ o_flat, const bf16* __restrict__ woT,
    float* __restrict__ out) {
    __shared__ __align__(16) unsigned char alds[16384];
    const int m0   = blockIdx.x * 128;
    const int col0 = blockIdx.y * 64;
    const int t = threadIdx.x;
    const int w = t >> 6, l = t & 63;
    const int lr = l & 15, lg = l >> 4;
    const int srow = t >> 3;           // 0..31 (+it*32)
    const int scb  = (t & 7) * 16;     // staging byte col (row = 128B)

    f32x4 acc[2][4] = {};
    for (int kk = 0; kk < D_; kk += 64) {
        bf16x8 st[4];
#pragma unroll
        for (int it = 0; it < 4; ++it)
            st[it] = *reinterpret_cast<const bf16x8*>(
                o_flat + (size_t)(m0 + srow + it * 32) * D_ + kk + (t & 7) * 8);
        __syncthreads();
#pragma unroll
        for (int it = 0; it < 4; ++it) {
            const int r = srow + it * 32;
            *reinterpret_cast<bf16x8*>(alds + r * 128 + (scb ^ ((r & 7) << 4))) = st[it];
        }
        __syncthreads();
#pragma unroll
        for (int ks = 0; ks < 2; ++ks) {
            bf16x8 a[2];
#pragma unroll
            for (int mf = 0; mf < 2; ++mf) {
                const int row = w * 32 + mf * 16 + lr;
                a[mf] = *reinterpret_cast<const bf16x8*>(
                    alds + row * 128 + ((ks * 64 + lg * 16) ^ ((row & 7) << 4)));
            }
#pragma unroll
            for (int nf = 0; nf < 4; ++nf) {
                const bf16x8 bb = *reinterpret_cast<const bf16x8*>(
                    woT + ((size_t)col0 + nf * 16 + lr) * D_ + kk + ks * 32 + lg * 8);
#pragma unroll
                for (int mf = 0; mf < 2; ++mf)
                    acc[mf][nf] = mfma16(a[mf], bb, acc[mf][nf]);
            }
        }
    }
#pragma unroll
    for (int mf = 0; mf < 2; ++mf)
#pragma unroll
        for (int nf = 0; nf < 4; ++nf)
#pragma unroll
            for (int i = 0; i < 4; ++i) {
                const int m = m0 + w * 32 + mf * 16 + lg * 4 + i;
                out[(size_t)m * D_ + col0 + nf * 16 + lr] = acc[mf][nf][i];
            }
}

// ---------------------------------------------------------------------------
extern "C" void kernel_launch(void* const* d_in, const int* in_sizes, int n_in,
                              void* d_out, int out_size, void* d_ws, size_t ws_size,
                              hipStream_t stream) {
    const float* q  = (const float*)d_in[0];
    const float* k  = (const float*)d_in[1];
    const float* v  = (const float*)d_in[2];
    const float* wq = (const float*)d_in[3];
    const float* wk = (const float*)d_in[4];
    const float* wv = (const float*)d_in[5];
    const float* wo = (const float*)d_in[6];
    float* out = (float*)d_out;

    char* p = (char*)d_ws;
    auto alloc = [&](size_t elems) {
        bf16* r = (bf16*)p;
        p += ((elems * 2 + 255) / 256) * 256;
        return r;
    };
    bf16* v_bf   = alloc((size_t)B_ * N_ * D_);
    bf16* wqT_hi = alloc((size_t)H_ * DK_ * D_);
    bf16* wqT_lo = alloc((size_t)H_ * DK_ * D_);
    bf16* wkT_hi = alloc((size_t)H_ * DK_ * D_);
    bf16* wkT_lo = alloc((size_t)H_ * DK_ * D_);
    bf16* wvT    = alloc((size_t)H_ * DK_ * D_);
    bf16* woT    = alloc((size_t)D_ * D_);
    bf16* qh_hi  = alloc((size_t)B_ * H_ * N_ * DK_);
    bf16* qh_lo  = alloc((size_t)B_ * H_ * N_ * DK_);
    bf16* kh_hi  = alloc((size_t)B_ * H_ * N_ * DK_);
    bf16* kh_lo  = alloc((size_t)B_ * H_ * N_ * DK_);
    bf16* vhT    = alloc((size_t)B_ * H_ * DK_ * N_);
    bf16* o_flat = alloc((size_t)B_ * N_ * H_ * DK_);

    if ((size_t)(p - (char*)d_ws) > ws_size) return;  // ws too small: bail

    prep_kernel<<<dim3(1024, 5), 256, 0, stream>>>(v, wq, wk, wv, wo, v_bf,
                                                   wqT_hi, wqT_lo, wkT_hi, wkT_lo, wvT, woT);
    proj_qk_kernel<<<dim3(64, 8), 256, 0, stream>>>(q, k, wqT_hi, wqT_lo, wkT_hi, wkT_lo,
                                                    qh_hi, qh_lo, kh_hi, kh_lo);
    proj_v_kernel<<<dim3(32, 64), 256, 0, stream>>>(v_bf, wvT, vhT);
    attn_kernel<<<1024, 256, 0, stream>>>(qh_hi, qh_lo, kh_hi, kh_lo, vhT, o_flat);
    outproj_kernel<<<dim3(64, 16), 256, 0, stream>>>(o_flat, woT, out);
}

// Round 7
// 467.912 us; speedup vs baseline: 2.9917x; 1.8682x over previous
//
#include <hip/hip_runtime.h>

// ---------------------------------------------------------------------------
// Fused multi-head attention (B=4, N=2048, D=1024, H=16, dk=dv=64, causal)
// R7: fragment-tiled operand layouts everywhere (64x64 tiles stored in MFMA
// consumption order -> every 16B/lane load = 1 contiguous KB = 1 transaction,
// vs 16 strided transactions before). attn: cooperative LDS staging of K/V
// tiles via global_load_lds, double-buffered, counted vmcnt, raw barriers.
// Numerics unchanged: split-bf16 Q/K path, DPP row-max, ones-column row-sum.
// ---------------------------------------------------------------------------

typedef short bf16;  // bf16 stored as raw bits
typedef short bf16x8 __attribute__((ext_vector_type(8)));
typedef float f32x4  __attribute__((ext_vector_type(4)));

constexpr int B_ = 4, N_ = 2048, D_ = 1024, H_ = 16, DK_ = 64;

static __device__ __forceinline__ bf16 f2bf(float f) {  // RNE float->bf16
    union { float f; unsigned u; } x; x.f = f;
    const unsigned r = x.u + 0x7FFFu + ((x.u >> 16) & 1u);
    return (bf16)(r >> 16);
}
static __device__ __forceinline__ float bf2f(bf16 s) {
    union { unsigned u; float f; } x; x.u = ((unsigned)(unsigned short)s) << 16;
    return x.f;
}
static __device__ __forceinline__ f32x4 mfma16(bf16x8 a, bf16x8 b, f32x4 c) {
    return __builtin_amdgcn_mfma_f32_16x16x32_bf16(a, b, c, 0, 0, 0);
}
template <int CTRL>
static __device__ __forceinline__ float dpp_mov(float x) {
    return __int_as_float(__builtin_amdgcn_update_dpp(
        __float_as_int(x), __float_as_int(x), CTRL, 0xF, 0xF, false));
}
static __device__ __forceinline__ float rowmax16(float x) {
    x = fmaxf(x, dpp_mov<0x128>(x));  // ror:8
    x = fmaxf(x, dpp_mov<0x124>(x));  // ror:4
    x = fmaxf(x, dpp_mov<0x122>(x));  // ror:2
    x = fmaxf(x, dpp_mov<0x121>(x));  // ror:1
    return x;
}
static __device__ __forceinline__ void gload16(const bf16* g, bf16* lds) {
    __builtin_amdgcn_global_load_lds(
        (const __attribute__((address_space(1))) void*)g,
        (__attribute__((address_space(3))) void*)lds, 16, 0, 0);
}

// Fragment-tile flat offset for a 64x64 operand tile, consumption order:
// elem(row,col) at (col>>5)*2048 + (row>>4)*512 + ((col>>3)&3)*128 + (row&15)*8 + (col&7)

// ---------------------------------------------------------------------------
// Kernel 0: prep — all weights + v into fragment-tiled bf16 layouts.
//   wq_t/wk_t: [h][kkt16][4096] hi+lo   (row=head col c, col=k-within-64)
//   wv_t:      [h][kkt16][4096]         (row=d, col=k)
//   wo_t:      [cg16][kkt16][4096]      (row=out col within 64, col=k)
//   v_t:       [b][st32][kkt16][4096]   (row=s within 64, col=d)
// Output-linear iteration (coalesced stores), gathered reads.
// ---------------------------------------------------------------------------
__global__ __launch_bounds__(256) void prep_kernel(
    const float* __restrict__ v,  const float* __restrict__ wq,
    const float* __restrict__ wk, const float* __restrict__ wv,
    const float* __restrict__ wo,
    bf16* __restrict__ v_t,
    bf16* __restrict__ wq_t_hi, bf16* __restrict__ wq_t_lo,
    bf16* __restrict__ wk_t_hi, bf16* __restrict__ wk_t_lo,
    bf16* __restrict__ wv_t, bf16* __restrict__ wo_t) {
    const int sec  = blockIdx.y;
    const int tid  = blockIdx.x * blockDim.x + threadIdx.x;
    const int nthr = gridDim.x * blockDim.x;
    if (sec == 0) {                       // v -> v_t
        const int n8 = (B_ * N_ * D_) / 8;
        for (int i8 = tid; i8 < n8; i8 += nthr) {
            const size_t o = (size_t)i8 * 8;
            const int e   = (int)(o & 4095);
            const int kkt = (int)((o >> 12) & 15);
            const int st  = (int)((o >> 16) & 31);
            const int b   = (int)(o >> 21);
            const int ks = e >> 11, f = (e >> 9) & 3, lg = (e >> 7) & 3, lr = (e >> 3) & 15;
            const int s = st * 64 + f * 16 + lr;
            const int d = kkt * 64 + ks * 32 + lg * 8;
            const float4* sp = reinterpret_cast<const float4*>(
                v + ((size_t)(b * N_ + s)) * D_ + d);
            const float4 f0 = sp[0], f1 = sp[1];
            const float ff[8] = {f0.x, f0.y, f0.z, f0.w, f1.x, f1.y, f1.z, f1.w};
            bf16x8 o8;
#pragma unroll
            for (int j = 0; j < 8; ++j) o8[j] = f2bf(ff[j]);
            *reinterpret_cast<bf16x8*>(v_t + o) = o8;
        }
    } else if (sec == 1 || sec == 2) {    // wq/wk -> tiled hi/lo
        const float* w = (sec == 1) ? wq : wk;
        bf16* whi = (sec == 1) ? wq_t_hi : wk_t_hi;
        bf16* wlo = (sec == 1) ? wq_t_lo : wk_t_lo;
        const int n8 = (H_ * DK_ * D_) / 8;
        for (int i8 = tid; i8 < n8; i8 += nthr) {
            const int o = i8 * 8;
            const int e = o & 4095, kkt = (o >> 12) & 15, h = o >> 16;
            const int ks = e >> 11, f = (e >> 9) & 3, lg = (e >> 7) & 3, lr = (e >> 3) & 15;
            const int c  = f * 16 + lr;
            const int kg = kkt * 64 + ks * 32 + lg * 8;
            bf16x8 h8, l8;
#pragma unroll
            for (int j = 0; j < 8; ++j) {
                const float fv = w[((size_t)h * D_ + kg + j) * DK_ + c];
                const bf16 hi = f2bf(fv);
                h8[j] = hi;
                l8[j] = f2bf(fv - bf2f(hi));
            }
            *reinterpret_cast<bf16x8*>(whi + o) = h8;
            *reinterpret_cast<bf16x8*>(wlo + o) = l8;
        }
    } else if (sec == 3) {                // wv -> wv_t (row=d)
        const int n8 = (H_ * DK_ * D_) / 8;
        for (int i8 = tid; i8 < n8; i8 += nthr) {
            const int o = i8 * 8;
            const int e = o & 4095, kkt = (o >> 12) & 15, h = o >> 16;
            const int ks = e >> 11, f = (e >> 9) & 3, lg = (e >> 7) & 3, lr = (e >> 3) & 15;
            const int d  = f * 16 + lr;
            const int kg = kkt * 64 + ks * 32 + lg * 8;
            bf16x8 o8;
#pragma unroll
            for (int j = 0; j < 8; ++j)
                o8[j] = f2bf(wv[((size_t)h * D_ + kg + j) * DK_ + d]);
            *reinterpret_cast<bf16x8*>(wv_t + o) = o8;
        }
    } else {                              // wo -> wo_t (row=out col)
        const int n8 = (D_ * D_) / 8;
        for (int i8 = tid; i8 < n8; i8 += nthr) {
            const int o = i8 * 8;
            const int e = o & 4095, kkt = (o >> 12) & 15, cg = o >> 16;
            const int ks = e >> 11, f = (e >> 9) & 3, lg = (e >> 7) & 3, lr = (e >> 3) & 15;
            const int c  = cg * 64 + f * 16 + lr;
            const int kg = kkt * 64 + ks * 32 + lg * 8;
            bf16x8 o8;
#pragma unroll
            for (int j = 0; j < 8; ++j)
                o8[j] = f2bf(wo[(size_t)(kg + j) * D_ + c]);
            *reinterpret_cast<bf16x8*>(wo_t + o) = o8;
        }
    }
}

// ---------------------------------------------------------------------------
// Kernel 1: Q/K projection, split-bf16, LDS-staged A, 128x256 tile.
// B from fragment-tiled weights (1-transaction loads). Q out row-major
// (hi/lo); K out fragment-tiled kh_t (hi/lo) for attn staging.
// ---------------------------------------------------------------------------
__global__ __launch_bounds__(256, 2) void proj_qk_kernel(
    const float* __restrict__ q, const float* __restrict__ k,
    const bf16* __restrict__ wq_t_hi, const bf16* __restrict__ wq_t_lo,
    const bf16* __restrict__ wk_t_hi, const bf16* __restrict__ wk_t_lo,
    bf16* __restrict__ qh_hi, bf16* __restrict__ qh_lo,
    bf16* __restrict__ kh_t_hi, bf16* __restrict__ kh_t_lo) {
    __shared__ __align__(16) unsigned char alds[32768];  // hi @0, lo @16K
    const int mat = blockIdx.y >> 2;       // 0=q, 1=k
    const int cg  = blockIdx.y & 3;        // col group (4 heads)
    const float* x    = mat ? k : q;
    const bf16* wT_hi = mat ? wk_t_hi : wq_t_hi;
    const bf16* wT_lo = mat ? wk_t_lo : wq_t_lo;
    const float scale = mat ? 1.0f : 0.125f;

    const int m0 = blockIdx.x * 128;
    const int t  = threadIdx.x;
    const int w  = t >> 6;
    const int l  = t & 63;
    const int lr = l & 15, lg = l >> 4;
    const int srow = t >> 3;
    const int scol = (t & 7) * 8;
    const int h = cg * 4 + w;              // wave's head

    f32x4 acc[8][4] = {};
    for (int kk = 0; kk < D_; kk += 64) {
        float4 st[4][2];
#pragma unroll
        for (int it = 0; it < 4; ++it) {
            const float4* ap = reinterpret_cast<const float4*>(
                x + (size_t)(m0 + srow + it * 32) * D_ + kk + scol);
            st[it][0] = ap[0]; st[it][1] = ap[1];
        }
        __syncthreads();
#pragma unroll
        for (int it = 0; it < 4; ++it) {
            const int r = srow + it * 32;
            const float ff[8] = {st[it][0].x, st[it][0].y, st[it][0].z, st[it][0].w,
                                 st[it][1].x, st[it][1].y, st[it][1].z, st[it][1].w};
            bf16x8 hi8, lo8;
#pragma unroll
            for (int j = 0; j < 8; ++j) {
                const float f   = ff[j] * scale;
                const bf16 hiv = f2bf(f);
                hi8[j] = hiv;
                lo8[j] = f2bf(f - bf2f(hiv));
            }
            const int byte = r * 128 + ((scol * 2) ^ ((r & 7) << 4));
            *reinterpret_cast<bf16x8*>(alds + byte)         = hi8;
            *reinterpret_cast<bf16x8*>(alds + 16384 + byte) = lo8;
        }
        __syncthreads();
        const int kkt = kk >> 6;
#pragma unroll
        for (int ks = 0; ks < 2; ++ks) {
            bf16x8 a_hi[8], a_lo[8];
#pragma unroll
            for (int mf = 0; mf < 8; ++mf) {
                const int row  = mf * 16 + lr;
                const int byte = row * 128 + ((ks * 64 + lg * 16) ^ ((row & 7) << 4));
                a_hi[mf] = *reinterpret_cast<const bf16x8*>(alds + byte);
                a_lo[mf] = *reinterpret_cast<const bf16x8*>(alds + 16384 + byte);
            }
#pragma unroll
            for (int nf = 0; nf < 4; ++nf) {
                const size_t boff = ((size_t)(h * 16 + kkt)) * 4096 +
                                    ks * 2048 + nf * 512 + lg * 128 + lr * 8;
                const bf16x8 b_hi = *reinterpret_cast<const bf16x8*>(wT_hi + boff);
                const bf16x8 b_lo = *reinterpret_cast<const bf16x8*>(wT_lo + boff);
#pragma unroll
                for (int mf = 0; mf < 8; ++mf) {
                    acc[mf][nf] = mfma16(a_hi[mf], b_hi, acc[mf][nf]);
                    acc[mf][nf] = mfma16(a_hi[mf], b_lo, acc[mf][nf]);
                    acc[mf][nf] = mfma16(a_lo[mf], b_hi, acc[mf][nf]);
                }
            }
        }
    }
#pragma unroll
    for (int mf = 0; mf < 8; ++mf)
#pragma unroll
        for (int nf = 0; nf < 4; ++nf)
#pragma unroll
            for (int i = 0; i < 4; ++i) {
                const int m = m0 + mf * 16 + lg * 4 + i;
                const int b = m >> 11, n = m & (N_ - 1);
                const float val = acc[mf][nf][i];
                const bf16 hi = f2bf(val);
                const bf16 lo = f2bf(val - bf2f(hi));
                if (mat == 0) {           // Q row-major [bh][n][c]
                    const int c = nf * 16 + lr;
                    const size_t oidx = (((size_t)(b * H_ + h)) * N_ + n) * DK_ + c;
                    qh_hi[oidx] = hi;
                    qh_lo[oidx] = lo;
                } else {                  // K fragment-tiled per (bh, st)
                    const size_t oidx =
                        ((size_t)(b * H_ + h) * 32 + (n >> 6)) * 4096 +
                        (nf >> 1) * 2048 + (mf & 3) * 512 +
                        (((nf << 1) + (lr >> 3)) & 3) * 128 +
                        (lg * 4 + i) * 8 + (lr & 7);
                    kh_t_hi[oidx] = hi;
                    kh_t_lo[oidx] = lo;
                }
            }
}

// ---------------------------------------------------------------------------
// Kernel 2: V projection (swapped operands) -> vh_t fragment-tiled
// [bh][st][4096] (row=d, col=s within 64). A/B from tiled layouts.
// grid (N/64, B*H).
// ---------------------------------------------------------------------------
__global__ __launch_bounds__(256) void proj_v_kernel(
    const bf16* __restrict__ v_t, const bf16* __restrict__ wv_t,
    bf16* __restrict__ vh_t) {
    const int bh = blockIdx.y;
    const int b = bh >> 4, h = bh & 15;
    const int st = blockIdx.x;
    const int w = threadIdx.x >> 6, l = threadIdx.x & 63;
    const int lr = l & 15, lg = l >> 4;

    f32x4 acc[4] = {};
    for (int kk = 0; kk < D_; kk += 32) {
        const int kkt = kk >> 6, ks = (kk >> 5) & 1;
        const bf16x8 a = *reinterpret_cast<const bf16x8*>(
            wv_t + ((size_t)(h * 16 + kkt)) * 4096 + ks * 2048 + w * 512 + lg * 128 + lr * 8);
#pragma unroll
        for (int nf = 0; nf < 4; ++nf) {
            const bf16x8 bb = *reinterpret_cast<const bf16x8*>(
                v_t + ((size_t)((b * 32 + st) * 16 + kkt)) * 4096 +
                ks * 2048 + nf * 512 + lg * 128 + lr * 8);
            acc[nf] = mfma16(a, bb, acc[nf]);
        }
    }
#pragma unroll
    for (int nf = 0; nf < 4; ++nf)
#pragma unroll
        for (int i = 0; i < 4; ++i) {
            const size_t oidx =
                ((size_t)(b * H_ + h) * 32 + st) * 4096 +
                (nf >> 1) * 2048 + w * 512 +
                (((nf << 1) + (lr >> 3)) & 3) * 128 +
                (lg * 4 + i) * 8 + (lr & 7);
            vh_t[oidx] = f2bf(acc[nf][i]);
        }
}

// ---------------------------------------------------------------------------
// Kernel 3: causal flash attention with cooperative LDS staging.
// 512 blocks (2/CU), each = one (bh, p8): 4 q-tiles {p8, 31-p8, p8+8, 23-p8}
// = 66 KV tiles uniform. Per tile: 4 waves stage K_hi/K_lo/V (24 KB linear,
// fragment-ordered) via global_load_lds, double-buffered, vmcnt(6) counted.
// ---------------------------------------------------------------------------
static __device__ __forceinline__ void stage_tile(
    const bf16* khh, const bf16* khl, const bf16* vht,
    bf16* buf, int st, int w, int l) {
    const bf16* kh = khh + (size_t)st * 4096;
    const bf16* kl = khl + (size_t)st * 4096;
    const bf16* vv = vht + (size_t)st * 4096;
#pragma unroll
    for (int i = 0; i < 6; ++i) {
        const int c = w * 6 + i;
        const bf16* src = (c < 8) ? kh + c * 512
                        : (c < 16) ? kl + (c - 8) * 512
                                   : vv + (c - 16) * 512;
        gload16(src + l * 8, buf + c * 512);
    }
}

__global__ __launch_bounds__(256, 2) void attn_kernel(
    const bf16* __restrict__ qh_hi, const bf16* __restrict__ qh_lo,
    const bf16* __restrict__ kh_t_hi, const bf16* __restrict__ kh_t_lo,
    const bf16* __restrict__ vh_t, bf16* __restrict__ o_flat) {
    __shared__ __align__(16) bf16 lds[2 * 12288 + 4 * 1024];  // 2 stage bufs + P
    const int bid  = blockIdx.x;
    const int wgid = (bid & 7) * 64 + (bid >> 3);   // 512 = 8*64 bijective
    const int bh   = wgid >> 3;
    const int p8   = wgid & 7;
    const int b = bh >> 4, h = bh & 15;
    const int w = threadIdx.x >> 6, l = threadIdx.x & 63;
    const int lr = l & 15, lg = l >> 4;
    unsigned char* myp = (unsigned char*)(lds + 24576 + w * 1024);
    const size_t hb = (size_t)(b * H_ + h);
    const bf16* khh = kh_t_hi + hb * 32 * 4096;
    const bf16* khl = kh_t_lo + hb * 32 * 4096;
    const bf16* vht = vh_t    + hb * 32 * 4096;

    bf16x8 ones;
#pragma unroll
    for (int j = 0; j < 8; ++j) ones[j] = (bf16)0x3F80;

    for (int phase = 0; phase < 4; ++phase) {
        const int qt = (phase == 0) ? p8 : (phase == 1) ? 31 - p8
                     : (phase == 2) ? p8 + 8 : 23 - p8;
        const int q0 = qt * 64 + w * 16;

        bf16x8 qf_hi[2], qf_lo[2];
#pragma unroll
        for (int ks = 0; ks < 2; ++ks) {
            const size_t off = (hb * N_ + q0 + lr) * DK_ + ks * 32 + lg * 8;
            qf_hi[ks] = *reinterpret_cast<const bf16x8*>(qh_hi + off);
            qf_lo[ks] = *reinterpret_cast<const bf16x8*>(qh_lo + off);
        }

        f32x4 m_run, l_acc, o_acc[4];
#pragma unroll
        for (int i = 0; i < 4; ++i) { m_run[i] = -3e38f; l_acc[i] = 0.f; }
#pragma unroll
        for (int dt = 0; dt < 4; ++dt) o_acc[dt] = f32x4{0.f, 0.f, 0.f, 0.f};

        const int nt = qt + 1;
        stage_tile(khh, khl, vht, lds, 0, w, l);          // prologue: tile 0 -> buf0
        for (int t = 0; t < nt; ++t) {
            bf16* cur = lds + (t & 1) * 12288;
            bf16* nxt = lds + ((t + 1) & 1) * 12288;
            if (t + 1 < nt) {
                stage_tile(khh, khl, vht, nxt, t + 1, w, l);
                asm volatile("s_waitcnt vmcnt(6)" ::: "memory");
            } else {
                asm volatile("s_waitcnt vmcnt(0)" ::: "memory");
            }
            __builtin_amdgcn_s_barrier();
            // ---- compute from cur ----
            const int s0 = t * 64;
            f32x4 sacc[4];
#pragma unroll
            for (int f = 0; f < 4; ++f) {
                sacc[f] = f32x4{0.f, 0.f, 0.f, 0.f};
#pragma unroll
                for (int ks = 0; ks < 2; ++ks) {
                    const bf16x8 khi = *reinterpret_cast<const bf16x8*>(
                        cur + ks * 2048 + f * 512 + l * 8);
                    const bf16x8 klo = *reinterpret_cast<const bf16x8*>(
                        cur + 4096 + ks * 2048 + f * 512 + l * 8);
                    sacc[f] = mfma16(qf_hi[ks], khi, sacc[f]);
                    sacc[f] = mfma16(qf_hi[ks], klo, sacc[f]);
                    sacc[f] = mfma16(qf_lo[ks], khi, sacc[f]);
                }
            }
            if (t == nt - 1) {  // diagonal tile: mask s > q
#pragma unroll
                for (int f = 0; f < 4; ++f) {
                    const int s = s0 + f * 16 + lr;
#pragma unroll
                    for (int i = 0; i < 4; ++i) {
                        const int qq = q0 + lg * 4 + i;
                        if (s > qq) sacc[f][i] = -1e9f;
                    }
                }
            }
            f32x4 m_new, escale;
#pragma unroll
            for (int i = 0; i < 4; ++i) {
                float tm = fmaxf(fmaxf(sacc[0][i], sacc[1][i]),
                                 fmaxf(sacc[2][i], sacc[3][i]));
                tm = rowmax16(tm);
                m_new[i]  = fmaxf(m_run[i], tm);
                escale[i] = __expf(m_run[i] - m_new[i]);
                m_run[i]  = m_new[i];
            }
#pragma unroll
            for (int f = 0; f < 4; ++f)
#pragma unroll
                for (int i = 0; i < 4; ++i) {
                    const float p = __expf(sacc[f][i] - m_new[i]);
                    const int row = lg * 4 + i, col = f * 16 + lr;
                    const int byte = (row * 128 + col * 2) ^ ((row & 7) << 4);
                    *reinterpret_cast<bf16*>(myp + byte) = f2bf(p);
                }
#pragma unroll
            for (int i = 0; i < 4; ++i) l_acc[i] *= escale[i];
#pragma unroll
            for (int dt = 0; dt < 4; ++dt)
#pragma unroll
                for (int i = 0; i < 4; ++i) o_acc[dt][i] *= escale[i];
            bf16x8 pa[2];
#pragma unroll
            for (int ks = 0; ks < 2; ++ks) {
                const int byte = (lr * 128 + ks * 64 + lg * 16) ^ ((lr & 7) << 4);
                pa[ks] = *reinterpret_cast<const bf16x8*>(myp + byte);
            }
#pragma unroll
            for (int dt = 0; dt < 4; ++dt)
#pragma unroll
                for (int ks = 0; ks < 2; ++ks) {
                    const bf16x8 vb = *reinterpret_cast<const bf16x8*>(
                        cur + 8192 + ks * 2048 + dt * 512 + l * 8);
                    o_acc[dt] = mfma16(pa[ks], vb, o_acc[dt]);
                }
#pragma unroll
            for (int ks = 0; ks < 2; ++ks)       // row-sum column: V = ones
                l_acc = mfma16(pa[ks], ones, l_acc);
            asm volatile("s_waitcnt lgkmcnt(0)" ::: "memory");
            __builtin_amdgcn_s_barrier();
        }
#pragma unroll
        for (int dt = 0; dt < 4; ++dt)
#pragma unroll
            for (int i = 0; i < 4; ++i) {
                const int qq = q0 + lg * 4 + i;
                const float val = o_acc[dt][i] / l_acc[i];
                o_flat[((size_t)b * N_ + qq) * (H_ * DK_) + h * DK_ + dt * 16 + lr] =
                    f2bf(val);
            }
    }
}

// ---------------------------------------------------------------------------
// Kernel 4: output projection; A via LDS staging, B from wo_t tiled.
// grid (64, 16), BK=64.
// ---------------------------------------------------------------------------
__global__ __launch_bounds__(256, 4) void outproj_kernel(
    const bf16* __restrict__ o_flat, const bf16* __restrict__ wo_t,
    float* __restrict__ out) {
    __shared__ __align__(16) unsigned char alds[16384];
    const int m0 = blockIdx.x * 128;
    const int cg = blockIdx.y;
    const int t = threadIdx.x;
    const int w = t >> 6, l = t & 63;
    const int lr = l & 15, lg = l >> 4;
    const int srow = t >> 3;
    const int scb  = (t & 7) * 16;

    f32x4 acc[2][4] = {};
    for (int kk = 0; kk < D_; kk += 64) {
        bf16x8 st[4];
#pragma unroll
        for (int it = 0; it < 4; ++it)
            st[it] = *reinterpret_cast<const bf16x8*>(
                o_flat + (size_t)(m0 + srow + it * 32) * D_ + kk + (t & 7) * 8);
        __syncthreads();
#pragma unroll
        for (int it = 0; it < 4; ++it) {
            const int r = srow + it * 32;
            *reinterpret_cast<bf16x8*>(alds + r * 128 + (scb ^ ((r & 7) << 4))) = st[it];
        }
        __syncthreads();
        const int kkt = kk >> 6;
#pragma unroll
        for (int ks = 0; ks < 2; ++ks) {
            bf16x8 a[2];
#pragma unroll
            for (int mf = 0; mf < 2; ++mf) {
                const int row = w * 32 + mf * 16 + lr;
                a[mf] = *reinterpret_cast<const bf16x8*>(
                    alds + row * 128 + ((ks * 64 + lg * 16) ^ ((row & 7) << 4)));
            }
#pragma unroll
            for (int nf = 0; nf < 4; ++nf) {
                const bf16x8 bb = *reinterpret_cast<const bf16x8*>(
                    wo_t + ((size_t)(cg * 16 + kkt)) * 4096 +
                    ks * 2048 + nf * 512 + lg * 128 + lr * 8);
#pragma unroll
                for (int mf = 0; mf < 2; ++mf)
                    acc[mf][nf] = mfma16(a[mf], bb, acc[mf][nf]);
            }
        }
    }
#pragma unroll
    for (int mf = 0; mf < 2; ++mf)
#pragma unroll
        for (int nf = 0; nf < 4; ++nf)
#pragma unroll
            for (int i = 0; i < 4; ++i) {
                const int m = m0 + w * 32 + mf * 16 + lg * 4 + i;
                out[(size_t)m * D_ + cg * 64 + nf * 16 + lr] = acc[mf][nf][i];
            }
}

// ---------------------------------------------------------------------------
extern "C" void kernel_launch(void* const* d_in, const int* in_sizes, int n_in,
                              void* d_out, int out_size, void* d_ws, size_t ws_size,
                              hipStream_t stream) {
    const float* q  = (const float*)d_in[0];
    const float* k  = (const float*)d_in[1];
    const float* v  = (const float*)d_in[2];
    const float* wq = (const float*)d_in[3];
    const float* wk = (const float*)d_in[4];
    const float* wv = (const float*)d_in[5];
    const float* wo = (const float*)d_in[6];
    float* out = (float*)d_out;

    char* p = (char*)d_ws;
    auto alloc = [&](size_t elems) {
        bf16* r = (bf16*)p;
        p += ((elems * 2 + 255) / 256) * 256;
        return r;
    };
    bf16* v_t     = alloc((size_t)B_ * N_ * D_);
    bf16* wq_t_hi = alloc((size_t)H_ * DK_ * D_);
    bf16* wq_t_lo = alloc((size_t)H_ * DK_ * D_);
    bf16* wk_t_hi = alloc((size_t)H_ * DK_ * D_);
    bf16* wk_t_lo = alloc((size_t)H_ * DK_ * D_);
    bf16* wv_t    = alloc((size_t)H_ * DK_ * D_);
    bf16* wo_t    = alloc((size_t)D_ * D_);
    bf16* qh_hi   = alloc((size_t)B_ * H_ * N_ * DK_);
    bf16* qh_lo   = alloc((size_t)B_ * H_ * N_ * DK_);
    bf16* kh_t_hi = alloc((size_t)B_ * H_ * N_ * DK_);
    bf16* kh_t_lo = alloc((size_t)B_ * H_ * N_ * DK_);
    bf16* vh_t    = alloc((size_t)B_ * H_ * DK_ * N_);
    bf16* o_flat  = alloc((size_t)B_ * N_ * H_ * DK_);

    if ((size_t)(p - (char*)d_ws) > ws_size) return;  // ws too small: bail

    prep_kernel<<<dim3(1024, 5), 256, 0, stream>>>(v, wq, wk, wv, wo, v_t,
                                                   wq_t_hi, wq_t_lo, wk_t_hi, wk_t_lo,
                                                   wv_t, wo_t);
    proj_qk_kernel<<<dim3(64, 8), 256, 0, stream>>>(q, k, wq_t_hi, wq_t_lo,
                                                    wk_t_hi, wk_t_lo,
                                                    qh_hi, qh_lo, kh_t_hi, kh_t_lo);
    proj_v_kernel<<<dim3(32, 64), 256, 0, stream>>>(v_t, wv_t, vh_t);
    attn_kernel<<<512, 256, 0, stream>>>(qh_hi, qh_lo, kh_t_hi, kh_t_lo, vh_t, o_flat);
    outproj_kernel<<<dim3(64, 16), 256, 0, stream>>>(o_flat, wo_t, out);
}

// Round 9
// 464.416 us; speedup vs baseline: 3.0142x; 1.0075x over previous
//
#include <hip/hip_runtime.h>

// ---------------------------------------------------------------------------
// Fused multi-head attention (B=4, N=2048, D=1024, H=16, dk=dv=64, causal)
// R8 (resubmit after infra timeout): attn restructured to 32 q-rows/wave
// (128-row band/block, band pairs (p,15-p) -> 34 uniform KV tiles) so staged
// K/V LDS reads serve 2x work; fully-masked tiles skipped per wave. outproj
// widened to 128-col blocks. Fragment-tiled operand layouts + gload_lds
// double-buffered staging kept. Numerics unchanged.
// ---------------------------------------------------------------------------

typedef short bf16;  // bf16 stored as raw bits
typedef short bf16x8 __attribute__((ext_vector_type(8)));
typedef float f32x4  __attribute__((ext_vector_type(4)));

constexpr int B_ = 4, N_ = 2048, D_ = 1024, H_ = 16, DK_ = 64;

static __device__ __forceinline__ bf16 f2bf(float f) {  // RNE float->bf16
    union { float f; unsigned u; } x; x.f = f;
    const unsigned r = x.u + 0x7FFFu + ((x.u >> 16) & 1u);
    return (bf16)(r >> 16);
}
static __device__ __forceinline__ float bf2f(bf16 s) {
    union { unsigned u; float f; } x; x.u = ((unsigned)(unsigned short)s) << 16;
    return x.f;
}
static __device__ __forceinline__ f32x4 mfma16(bf16x8 a, bf16x8 b, f32x4 c) {
    return __builtin_amdgcn_mfma_f32_16x16x32_bf16(a, b, c, 0, 0, 0);
}
template <int CTRL>
static __device__ __forceinline__ float dpp_mov(float x) {
    return __int_as_float(__builtin_amdgcn_update_dpp(
        __float_as_int(x), __float_as_int(x), CTRL, 0xF, 0xF, false));
}
static __device__ __forceinline__ float rowmax16(float x) {
    x = fmaxf(x, dpp_mov<0x128>(x));  // ror:8
    x = fmaxf(x, dpp_mov<0x124>(x));  // ror:4
    x = fmaxf(x, dpp_mov<0x122>(x));  // ror:2
    x = fmaxf(x, dpp_mov<0x121>(x));  // ror:1
    return x;
}
static __device__ __forceinline__ void gload16(const bf16* g, bf16* lds) {
    __builtin_amdgcn_global_load_lds(
        (const __attribute__((address_space(1))) void*)g,
        (__attribute__((address_space(3))) void*)lds, 16, 0, 0);
}

// ---------------------------------------------------------------------------
// Kernel 0: prep — all weights + v into fragment-tiled bf16 layouts. (as R7)
// ---------------------------------------------------------------------------
__global__ __launch_bounds__(256) void prep_kernel(
    const float* __restrict__ v,  const float* __restrict__ wq,
    const float* __restrict__ wk, const float* __restrict__ wv,
    const float* __restrict__ wo,
    bf16* __restrict__ v_t,
    bf16* __restrict__ wq_t_hi, bf16* __restrict__ wq_t_lo,
    bf16* __restrict__ wk_t_hi, bf16* __restrict__ wk_t_lo,
    bf16* __restrict__ wv_t, bf16* __restrict__ wo_t) {
    const int sec  = blockIdx.y;
    const int tid  = blockIdx.x * blockDim.x + threadIdx.x;
    const int nthr = gridDim.x * blockDim.x;
    if (sec == 0) {                       // v -> v_t
        const int n8 = (B_ * N_ * D_) / 8;
        for (int i8 = tid; i8 < n8; i8 += nthr) {
            const size_t o = (size_t)i8 * 8;
            const int e   = (int)(o & 4095);
            const int kkt = (int)((o >> 12) & 15);
            const int st  = (int)((o >> 16) & 31);
            const int b   = (int)(o >> 21);
            const int ks = e >> 11, f = (e >> 9) & 3, lg = (e >> 7) & 3, lr = (e >> 3) & 15;
            const int s = st * 64 + f * 16 + lr;
            const int d = kkt * 64 + ks * 32 + lg * 8;
            const float4* sp = reinterpret_cast<const float4*>(
                v + ((size_t)(b * N_ + s)) * D_ + d);
            const float4 f0 = sp[0], f1 = sp[1];
            const float ff[8] = {f0.x, f0.y, f0.z, f0.w, f1.x, f1.y, f1.z, f1.w};
            bf16x8 o8;
#pragma unroll
            for (int j = 0; j < 8; ++j) o8[j] = f2bf(ff[j]);
            *reinterpret_cast<bf16x8*>(v_t + o) = o8;
        }
    } else if (sec == 1 || sec == 2) {    // wq/wk -> tiled hi/lo
        const float* w = (sec == 1) ? wq : wk;
        bf16* whi = (sec == 1) ? wq_t_hi : wk_t_hi;
        bf16* wlo = (sec == 1) ? wq_t_lo : wk_t_lo;
        const int n8 = (H_ * DK_ * D_) / 8;
        for (int i8 = tid; i8 < n8; i8 += nthr) {
            const int o = i8 * 8;
            const int e = o & 4095, kkt = (o >> 12) & 15, h = o >> 16;
            const int ks = e >> 11, f = (e >> 9) & 3, lg = (e >> 7) & 3, lr = (e >> 3) & 15;
            const int c  = f * 16 + lr;
            const int kg = kkt * 64 + ks * 32 + lg * 8;
            bf16x8 h8, l8;
#pragma unroll
            for (int j = 0; j < 8; ++j) {
                const float fv = w[((size_t)h * D_ + kg + j) * DK_ + c];
                const bf16 hi = f2bf(fv);
                h8[j] = hi;
                l8[j] = f2bf(fv - bf2f(hi));
            }
            *reinterpret_cast<bf16x8*>(whi + o) = h8;
            *reinterpret_cast<bf16x8*>(wlo + o) = l8;
        }
    } else if (sec == 3) {                // wv -> wv_t (row=d)
        const int n8 = (H_ * DK_ * D_) / 8;
        for (int i8 = tid; i8 < n8; i8 += nthr) {
            const int o = i8 * 8;
            const int e = o & 4095, kkt = (o >> 12) & 15, h = o >> 16;
            const int ks = e >> 11, f = (e >> 9) & 3, lg = (e >> 7) & 3, lr = (e >> 3) & 15;
            const int d  = f * 16 + lr;
            const int kg = kkt * 64 + ks * 32 + lg * 8;
            bf16x8 o8;
#pragma unroll
            for (int j = 0; j < 8; ++j)
                o8[j] = f2bf(wv[((size_t)h * D_ + kg + j) * DK_ + d]);
            *reinterpret_cast<bf16x8*>(wv_t + o) = o8;
        }
    } else {                              // wo -> wo_t (row=out col)
        const int n8 = (D_ * D_) / 8;
        for (int i8 = tid; i8 < n8; i8 += nthr) {
            const int o = i8 * 8;
            const int e = o & 4095, kkt = (o >> 12) & 15, cg = o >> 16;
            const int ks = e >> 11, f = (e >> 9) & 3, lg = (e >> 7) & 3, lr = (e >> 3) & 15;
            const int c  = cg * 64 + f * 16 + lr;
            const int kg = kkt * 64 + ks * 32 + lg * 8;
            bf16x8 o8;
#pragma unroll
            for (int j = 0; j < 8; ++j)
                o8[j] = f2bf(wo[(size_t)(kg + j) * D_ + c]);
            *reinterpret_cast<bf16x8*>(wo_t + o) = o8;
        }
    }
}

// ---------------------------------------------------------------------------
// Kernel 1: Q/K projection, split-bf16, LDS-staged A, 128x256 tile. (as R7)
// ---------------------------------------------------------------------------
__global__ __launch_bounds__(256, 2) void proj_qk_kernel(
    const float* __restrict__ q, const float* __restrict__ k,
    const bf16* __restrict__ wq_t_hi, const bf16* __restrict__ wq_t_lo,
    const bf16* __restrict__ wk_t_hi, const bf16* __restrict__ wk_t_lo,
    bf16* __restrict__ qh_hi, bf16* __restrict__ qh_lo,
    bf16* __restrict__ kh_t_hi, bf16* __restrict__ kh_t_lo) {
    __shared__ __align__(16) unsigned char alds[32768];  // hi @0, lo @16K
    const int mat = blockIdx.y >> 2;       // 0=q, 1=k
    const int cg  = blockIdx.y & 3;        // col group (4 heads)
    const float* x    = mat ? k : q;
    const bf16* wT_hi = mat ? wk_t_hi : wq_t_hi;
    const bf16* wT_lo = mat ? wk_t_lo : wq_t_lo;
    const float scale = mat ? 1.0f : 0.125f;

    const int m0 = blockIdx.x * 128;
    const int t  = threadIdx.x;
    const int w  = t >> 6;
    const int l  = t & 63;
    const int lr = l & 15, lg = l >> 4;
    const int srow = t >> 3;
    const int scol = (t & 7) * 8;
    const int h = cg * 4 + w;              // wave's head

    f32x4 acc[8][4] = {};
    for (int kk = 0; kk < D_; kk += 64) {
        float4 st[4][2];
#pragma unroll
        for (int it = 0; it < 4; ++it) {
            const float4* ap = reinterpret_cast<const float4*>(
                x + (size_t)(m0 + srow + it * 32) * D_ + kk + scol);
            st[it][0] = ap[0]; st[it][1] = ap[1];
        }
        __syncthreads();
#pragma unroll
        for (int it = 0; it < 4; ++it) {
            const int r = srow + it * 32;
            const float ff[8] = {st[it][0].x, st[it][0].y, st[it][0].z, st[it][0].w,
                                 st[it][1].x, st[it][1].y, st[it][1].z, st[it][1].w};
            bf16x8 hi8, lo8;
#pragma unroll
            for (int j = 0; j < 8; ++j) {
                const float f   = ff[j] * scale;
                const bf16 hiv = f2bf(f);
                hi8[j] = hiv;
                lo8[j] = f2bf(f - bf2f(hiv));
            }
            const int byte = r * 128 + ((scol * 2) ^ ((r & 7) << 4));
            *reinterpret_cast<bf16x8*>(alds + byte)         = hi8;
            *reinterpret_cast<bf16x8*>(alds + 16384 + byte) = lo8;
        }
        __syncthreads();
        const int kkt = kk >> 6;
#pragma unroll
        for (int ks = 0; ks < 2; ++ks) {
            bf16x8 a_hi[8], a_lo[8];
#pragma unroll
            for (int mf = 0; mf < 8; ++mf) {
                const int row  = mf * 16 + lr;
                const int byte = row * 128 + ((ks * 64 + lg * 16) ^ ((row & 7) << 4));
                a_hi[mf] = *reinterpret_cast<const bf16x8*>(alds + byte);
                a_lo[mf] = *reinterpret_cast<const bf16x8*>(alds + 16384 + byte);
            }
#pragma unroll
            for (int nf = 0; nf < 4; ++nf) {
                const size_t boff = ((size_t)(h * 16 + kkt)) * 4096 +
                                    ks * 2048 + nf * 512 + lg * 128 + lr * 8;
                const bf16x8 b_hi = *reinterpret_cast<const bf16x8*>(wT_hi + boff);
                const bf16x8 b_lo = *reinterpret_cast<const bf16x8*>(wT_lo + boff);
#pragma unroll
                for (int mf = 0; mf < 8; ++mf) {
                    acc[mf][nf] = mfma16(a_hi[mf], b_hi, acc[mf][nf]);
                    acc[mf][nf] = mfma16(a_hi[mf], b_lo, acc[mf][nf]);
                    acc[mf][nf] = mfma16(a_lo[mf], b_hi, acc[mf][nf]);
                }
            }
        }
    }
#pragma unroll
    for (int mf = 0; mf < 8; ++mf)
#pragma unroll
        for (int nf = 0; nf < 4; ++nf)
#pragma unroll
            for (int i = 0; i < 4; ++i) {
                const int m = m0 + mf * 16 + lg * 4 + i;
                const int b = m >> 11, n = m & (N_ - 1);
                const float val = acc[mf][nf][i];
                const bf16 hi = f2bf(val);
                const bf16 lo = f2bf(val - bf2f(hi));
                if (mat == 0) {           // Q row-major [bh][n][c]
                    const int c = nf * 16 + lr;
                    const size_t oidx = (((size_t)(b * H_ + h)) * N_ + n) * DK_ + c;
                    qh_hi[oidx] = hi;
                    qh_lo[oidx] = lo;
                } else {                  // K fragment-tiled per (bh, st)
                    const size_t oidx =
                        ((size_t)(b * H_ + h) * 32 + (n >> 6)) * 4096 +
                        (nf >> 1) * 2048 + (mf & 3) * 512 +
                        (((nf << 1) + (lr >> 3)) & 3) * 128 +
                        (lg * 4 + i) * 8 + (lr & 7);
                    kh_t_hi[oidx] = hi;
                    kh_t_lo[oidx] = lo;
                }
            }
}

// ---------------------------------------------------------------------------
// Kernel 2: V projection (swapped operands) -> vh_t fragment-tiled. (as R7)
// ---------------------------------------------------------------------------
__global__ __launch_bounds__(256) void proj_v_kernel(
    const bf16* __restrict__ v_t, const bf16* __restrict__ wv_t,
    bf16* __restrict__ vh_t) {
    const int bh = blockIdx.y;
    const int b = bh >> 4, h = bh & 15;
    const int st = blockIdx.x;
    const int w = threadIdx.x >> 6, l = threadIdx.x & 63;
    const int lr = l & 15, lg = l >> 4;

    f32x4 acc[4] = {};
    for (int kk = 0; kk < D_; kk += 32) {
        const int kkt = kk >> 6, ks = (kk >> 5) & 1;
        const bf16x8 a = *reinterpret_cast<const bf16x8*>(
            wv_t + ((size_t)(h * 16 + kkt)) * 4096 + ks * 2048 + w * 512 + lg * 128 + lr * 8);
#pragma unroll
        for (int nf = 0; nf < 4; ++nf) {
            const bf16x8 bb = *reinterpret_cast<const bf16x8*>(
                v_t + ((size_t)((b * 32 + st) * 16 + kkt)) * 4096 +
                ks * 2048 + nf * 512 + lg * 128 + lr * 8);
            acc[nf] = mfma16(a, bb, acc[nf]);
        }
    }
#pragma unroll
    for (int nf = 0; nf < 4; ++nf)
#pragma unroll
        for (int i = 0; i < 4; ++i) {
            const size_t oidx =
                ((size_t)(b * H_ + h) * 32 + st) * 4096 +
                (nf >> 1) * 2048 + w * 512 +
                (((nf << 1) + (lr >> 3)) & 3) * 128 +
                (lg * 4 + i) * 8 + (lr & 7);
            vh_t[oidx] = f2bf(acc[nf][i]);
        }
}

// ---------------------------------------------------------------------------
// Kernel 3: causal flash attention, 32 q-rows/wave.
// 512 blocks (2/CU): block = (bh, band-pair p8/(15-p8)); band = 128 q-rows
// (4 waves x 32). Per phase: nt = 2*(band+1) KV tiles, staged K_hi/K_lo/V
// (24 KB linear) via gload_lds, double-buffered, vmcnt(6). Waves skip
// fully-masked tiles (barriers kept).
// ---------------------------------------------------------------------------
static __device__ __forceinline__ void stage_tile(
    const bf16* khh, const bf16* khl, const bf16* vht,
    bf16* buf, int st, int w, int l) {
    const bf16* kh = khh + (size_t)st * 4096;
    const bf16* kl = khl + (size_t)st * 4096;
    const bf16* vv = vht + (size_t)st * 4096;
#pragma unroll
    for (int i = 0; i < 6; ++i) {
        const int c = w * 6 + i;
        const bf16* src = (c < 8) ? kh + c * 512
                        : (c < 16) ? kl + (c - 8) * 512
                                   : vv + (c - 16) * 512;
        gload16(src + l * 8, buf + c * 512);
    }
}

__global__ __launch_bounds__(256, 2) void attn_kernel(
    const bf16* __restrict__ qh_hi, const bf16* __restrict__ qh_lo,
    const bf16* __restrict__ kh_t_hi, const bf16* __restrict__ kh_t_lo,
    const bf16* __restrict__ vh_t, bf16* __restrict__ o_flat) {
    __shared__ __align__(16) bf16 lds[2 * 12288 + 4 * 2048];  // stage 48K + P 16K
    const int bid  = blockIdx.x;
    const int wgid = (bid & 7) * 64 + (bid >> 3);   // 512 = 8*64 bijective
    const int bh   = wgid >> 3;
    const int p8   = wgid & 7;
    const int b = bh >> 4, h = bh & 15;
    const int w = threadIdx.x >> 6, l = threadIdx.x & 63;
    const int lr = l & 15, lg = l >> 4;
    unsigned char* myp = (unsigned char*)(lds + 24576 + w * 2048);  // 4KB/wave
    const size_t hb = (size_t)(b * H_ + h);
    const bf16* khh = kh_t_hi + hb * 32 * 4096;
    const bf16* khl = kh_t_lo + hb * 32 * 4096;
    const bf16* vht = vh_t    + hb * 32 * 4096;

    bf16x8 ones;
#pragma unroll
    for (int j = 0; j < 8; ++j) ones[j] = (bf16)0x3F80;

    for (int phase = 0; phase < 2; ++phase) {
        const int band = phase ? (15 - p8) : p8;
        const int q0 = band * 128 + w * 32;    // wave's 32 q-rows

        bf16x8 qf_hi[2][2], qf_lo[2][2];
#pragma unroll
        for (int mf = 0; mf < 2; ++mf)
#pragma unroll
            for (int ks = 0; ks < 2; ++ks) {
                const size_t off = (hb * N_ + q0 + mf * 16 + lr) * DK_ + ks * 32 + lg * 8;
                qf_hi[mf][ks] = *reinterpret_cast<const bf16x8*>(qh_hi + off);
                qf_lo[mf][ks] = *reinterpret_cast<const bf16x8*>(qh_lo + off);
            }

        f32x4 m_run[2], l_acc[2], o_acc[2][4];
#pragma unroll
        for (int mf = 0; mf < 2; ++mf) {
#pragma unroll
            for (int i = 0; i < 4; ++i) { m_run[mf][i] = -3e38f; l_acc[mf][i] = 0.f; }
#pragma unroll
            for (int dt = 0; dt < 4; ++dt) o_acc[mf][dt] = f32x4{0.f, 0.f, 0.f, 0.f};
        }

        const int nt = 2 * (band + 1);
        stage_tile(khh, khl, vht, lds, 0, w, l);          // prologue
        for (int t = 0; t < nt; ++t) {
            bf16* cur = lds + (t & 1) * 12288;
            bf16* nxt = lds + ((t + 1) & 1) * 12288;
            if (t + 1 < nt) {
                stage_tile(khh, khl, vht, nxt, t + 1, w, l);
                asm volatile("s_waitcnt vmcnt(6)" ::: "memory");
            } else {
                asm volatile("s_waitcnt vmcnt(0)" ::: "memory");
            }
            __builtin_amdgcn_s_barrier();
            const int s0 = t * 64;
            if (s0 <= q0 + 31) {    // not fully masked for this wave
                f32x4 sacc[2][4];
#pragma unroll
                for (int mf = 0; mf < 2; ++mf)
#pragma unroll
                    for (int f = 0; f < 4; ++f)
                        sacc[mf][f] = f32x4{0.f, 0.f, 0.f, 0.f};
#pragma unroll
                for (int f = 0; f < 4; ++f)
#pragma unroll
                    for (int ks = 0; ks < 2; ++ks) {
                        const bf16x8 khi = *reinterpret_cast<const bf16x8*>(
                            cur + ks * 2048 + f * 512 + l * 8);
                        const bf16x8 klo = *reinterpret_cast<const bf16x8*>(
                            cur + 4096 + ks * 2048 + f * 512 + l * 8);
#pragma unroll
                        for (int mf = 0; mf < 2; ++mf) {
                            sacc[mf][f] = mfma16(qf_hi[mf][ks], khi, sacc[mf][f]);
                            sacc[mf][f] = mfma16(qf_hi[mf][ks], klo, sacc[mf][f]);
                            sacc[mf][f] = mfma16(qf_lo[mf][ks], khi, sacc[mf][f]);
                        }
                    }
                if (s0 + 63 > q0) {  // diagonal region: mask s > q
#pragma unroll
                    for (int mf = 0; mf < 2; ++mf)
#pragma unroll
                        for (int f = 0; f < 4; ++f) {
                            const int s = s0 + f * 16 + lr;
#pragma unroll
                            for (int i = 0; i < 4; ++i) {
                                const int qq = q0 + mf * 16 + lg * 4 + i;
                                if (s > qq) sacc[mf][f][i] = -1e9f;
                            }
                        }
                }
                f32x4 escale[2];
#pragma unroll
                for (int mf = 0; mf < 2; ++mf)
#pragma unroll
                    for (int i = 0; i < 4; ++i) {
                        float tm = fmaxf(fmaxf(sacc[mf][0][i], sacc[mf][1][i]),
                                         fmaxf(sacc[mf][2][i], sacc[mf][3][i]));
                        tm = rowmax16(tm);
                        const float mn = fmaxf(m_run[mf][i], tm);
                        escale[mf][i] = __expf(m_run[mf][i] - mn);
                        m_run[mf][i]  = mn;
                    }
#pragma unroll
                for (int mf = 0; mf < 2; ++mf)
#pragma unroll
                    for (int f = 0; f < 4; ++f)
#pragma unroll
                        for (int i = 0; i < 4; ++i) {
                            const float p = __expf(sacc[mf][f][i] - m_run[mf][i]);
                            const int row = mf * 16 + lg * 4 + i, col = f * 16 + lr;
                            const int byte = (row * 128 + col * 2) ^ ((row & 7) << 4);
                            *reinterpret_cast<bf16*>(myp + byte) = f2bf(p);
                        }
#pragma unroll
                for (int mf = 0; mf < 2; ++mf) {
#pragma unroll
                    for (int i = 0; i < 4; ++i) l_acc[mf][i] *= escale[mf][i];
#pragma unroll
                    for (int dt = 0; dt < 4; ++dt)
#pragma unroll
                        for (int i = 0; i < 4; ++i) o_acc[mf][dt][i] *= escale[mf][i];
                }
                bf16x8 pa[2][2];
#pragma unroll
                for (int mf = 0; mf < 2; ++mf)
#pragma unroll
                    for (int ks = 0; ks < 2; ++ks) {
                        const int row = mf * 16 + lr;
                        const int byte = (row * 128 + ks * 64 + lg * 16) ^ ((row & 7) << 4);
                        pa[mf][ks] = *reinterpret_cast<const bf16x8*>(myp + byte);
                    }
#pragma unroll
                for (int dt = 0; dt < 4; ++dt)
#pragma unroll
                    for (int ks = 0; ks < 2; ++ks) {
                        const bf16x8 vb = *reinterpret_cast<const bf16x8*>(
                            cur + 8192 + ks * 2048 + dt * 512 + l * 8);
#pragma unroll
                        for (int mf = 0; mf < 2; ++mf)
                            o_acc[mf][dt] = mfma16(pa[mf][ks], vb, o_acc[mf][dt]);
                    }
#pragma unroll
                for (int mf = 0; mf < 2; ++mf)
#pragma unroll
                    for (int ks = 0; ks < 2; ++ks)   // row-sum column: V = ones
                        l_acc[mf] = mfma16(pa[mf][ks], ones, l_acc[mf]);
            }
            asm volatile("s_waitcnt lgkmcnt(0)" ::: "memory");
            __builtin_amdgcn_s_barrier();
        }
#pragma unroll
        for (int mf = 0; mf < 2; ++mf)
#pragma unroll
            for (int dt = 0; dt < 4; ++dt)
#pragma unroll
                for (int i = 0; i < 4; ++i) {
                    const int qq = q0 + mf * 16 + lg * 4 + i;
                    const float val = o_acc[mf][dt][i] / l_acc[mf][i];
                    o_flat[((size_t)b * N_ + qq) * (H_ * DK_) + h * DK_ + dt * 16 + lr] =
                        f2bf(val);
                }
    }
}

// ---------------------------------------------------------------------------
// Kernel 4: output projection, 128x128 blocks. grid (64, 8), BK=64.
// ---------------------------------------------------------------------------
__global__ __launch_bounds__(256, 4) void outproj_kernel(
    const bf16* __restrict__ o_flat, const bf16* __restrict__ wo_t,
    float* __restrict__ out) {
    __shared__ __align__(16) unsigned char alds[16384];
    const int m0 = blockIdx.x * 128;
    const int cp = blockIdx.y;            // 128-col group
    const int t = threadIdx.x;
    const int w = t >> 6, l = t & 63;
    const int lr = l & 15, lg = l >> 4;
    const int srow = t >> 3;
    const int scb  = (t & 7) * 16;

    f32x4 acc[2][8] = {};
    for (int kk = 0; kk < D_; kk += 64) {
        bf16x8 st[4];
#pragma unroll
        for (int it = 0; it < 4; ++it)
            st[it] = *reinterpret_cast<const bf16x8*>(
                o_flat + (size_t)(m0 + srow + it * 32) * D_ + kk + (t & 7) * 8);
        __syncthreads();
#pragma unroll
        for (int it = 0; it < 4; ++it) {
            const int r = srow + it * 32;
            *reinterpret_cast<bf16x8*>(alds + r * 128 + (scb ^ ((r & 7) << 4))) = st[it];
        }
        __syncthreads();
        const int kkt = kk >> 6;
#pragma unroll
        for (int ks = 0; ks < 2; ++ks) {
            bf16x8 a[2];
#pragma unroll
            for (int mf = 0; mf < 2; ++mf) {
                const int row = w * 32 + mf * 16 + lr;
                a[mf] = *reinterpret_cast<const bf16x8*>(
                    alds + row * 128 + ((ks * 64 + lg * 16) ^ ((row & 7) << 4)));
            }
#pragma unroll
            for (int nf = 0; nf < 8; ++nf) {
                const int cg = cp * 2 + (nf >> 2);
                const bf16x8 bb = *reinterpret_cast<const bf16x8*>(
                    wo_t + ((size_t)(cg * 16 + kkt)) * 4096 +
                    ks * 2048 + (nf & 3) * 512 + lg * 128 + lr * 8);
#pragma unroll
                for (int mf = 0; mf < 2; ++mf)
                    acc[mf][nf] = mfma16(a[mf], bb, acc[mf][nf]);
            }
        }
    }
#pragma unroll
    for (int mf = 0; mf < 2; ++mf)
#pragma unroll
        for (int nf = 0; nf < 8; ++nf)
#pragma unroll
            for (int i = 0; i < 4; ++i) {
                const int m = m0 + w * 32 + mf * 16 + lg * 4 + i;
                const int c = (cp * 2 + (nf >> 2)) * 64 + (nf & 3) * 16 + lr;
                out[(size_t)m * D_ + c] = acc[mf][nf][i];
            }
}

// ---------------------------------------------------------------------------
extern "C" void kernel_launch(void* const* d_in, const int* in_sizes, int n_in,
                              void* d_out, int out_size, void* d_ws, size_t ws_size,
                              hipStream_t stream) {
    const float* q  = (const float*)d_in[0];
    const float* k  = (const float*)d_in[1];
    const float* v  = (const float*)d_in[2];
    const float* wq = (const float*)d_in[3];
    const float* wk = (const float*)d_in[4];
    const float* wv = (const float*)d_in[5];
    const float* wo = (const float*)d_in[6];
    float* out = (float*)d_out;

    char* p = (char*)d_ws;
    auto alloc = [&](size_t elems) {
        bf16* r = (bf16*)p;
        p += ((elems * 2 + 255) / 256) * 256;
        return r;
    };
    bf16* v_t     = alloc((size_t)B_ * N_ * D_);
    bf16* wq_t_hi = alloc((size_t)H_ * DK_ * D_);
    bf16* wq_t_lo = alloc((size_t)H_ * DK_ * D_);
    bf16* wk_t_hi = alloc((size_t)H_ * DK_ * D_);
    bf16* wk_t_lo = alloc((size_t)H_ * DK_ * D_);
    bf16* wv_t    = alloc((size_t)H_ * DK_ * D_);
    bf16* wo_t    = alloc((size_t)D_ * D_);
    bf16* qh_hi   = alloc((size_t)B_ * H_ * N_ * DK_);
    bf16* qh_lo   = alloc((size_t)B_ * H_ * N_ * DK_);
    bf16* kh_t_hi = alloc((size_t)B_ * H_ * N_ * DK_);
    bf16* kh_t_lo = alloc((size_t)B_ * H_ * N_ * DK_);
    bf16* vh_t    = alloc((size_t)B_ * H_ * DK_ * N_);
    bf16* o_flat  = alloc((size_t)B_ * N_ * H_ * DK_);

    if ((size_t)(p - (char*)d_ws) > ws_size) return;  // ws too small: bail

    prep_kernel<<<dim3(1024, 5), 256, 0, stream>>>(v, wq, wk, wv, wo, v_t,
                                                   wq_t_hi, wq_t_lo, wk_t_hi, wk_t_lo,
                                                   wv_t, wo_t);
    proj_qk_kernel<<<dim3(64, 8), 256, 0, stream>>>(q, k, wq_t_hi, wq_t_lo,
                                                    wk_t_hi, wk_t_lo,
                                                    qh_hi, qh_lo, kh_t_hi, kh_t_lo);
    proj_v_kernel<<<dim3(32, 64), 256, 0, stream>>>(v_t, wv_t, vh_t);
    attn_kernel<<<512, 256, 0, stream>>>(qh_hi, qh_lo, kh_t_hi, kh_t_lo, vh_t, o_flat);
    outproj_kernel<<<dim3(64, 8), 256, 0, stream>>>(o_flat, wo_t, out);
}